// Round 9
// baseline (43425.351 us; speedup 1.0000x reference)
//
#include <hip/hip_runtime.h>
#include <hip/hip_bf16.h>

#define VOCAB 200000
#define EMB 256
#define HID 512
#define SEQ 8192
#define TOK 32768
#define TAGS 512
#define G4H 2048  // 4*HID

#define SENT 0x7FBFFFFFu  // NaN payload sentinel; real h is always finite

typedef unsigned u4v __attribute__((ext_vector_type(4)));

__device__ __forceinline__ float sigmoidf_(float x) { return 1.0f / (1.0f + __expf(-x)); }
__device__ __forceinline__ float tanhf_(float x) { return 1.0f - 2.0f / (1.0f + __expf(2.0f * x)); }

// ------------- kernel 0: init (safe h buffer + election table + flags) -------
__global__ void init_sentinel(unsigned* __restrict__ hbuf, int n,
                              unsigned* __restrict__ tab, int ntab,
                              unsigned* __restrict__ flags, int nflags) {
  int i = blockIdx.x * blockDim.x + threadIdx.x;
  int stride = gridDim.x * blockDim.x;
  for (int k = i; k < n; k += stride) hbuf[k] = SENT;
  for (int k = i; k < ntab; k += stride) tab[k] = 0xFFFFFFFFu;
  for (int k = i; k < nflags; k += stride) flags[k] = 0u;
}

// ---------------- kernel 1: embedding bag (sum pool per sorted segment) ------
__global__ __launch_bounds__(256) void embed_pool(
    const float* __restrict__ emb, const int* __restrict__ ids,
    const int* __restrict__ seg, float* __restrict__ out) {
  int s = blockIdx.x;
  int d = threadIdx.x;  // 256 = EMB
  int lo = 0, hi = TOK;
  while (lo < hi) { int m = (lo + hi) >> 1; if (seg[m] < s) lo = m + 1; else hi = m; }
  int start = lo;
  hi = TOK;
  while (lo < hi) { int m = (lo + hi) >> 1; if (seg[m] < s + 1) lo = m + 1; else hi = m; }
  int end = lo;
  float acc = 0.f;
  for (int tkn = start; tkn < end; ++tkn) {
    acc += emb[(long)ids[tkn] * EMB + d];
  }
  out[s * EMB + d] = acc;
}

// ---------------- kernel 2: xg = embeds @ w_ih^T + b  (both dirs) ------------
__global__ __launch_bounds__(256) void xg_gemm(
    const float* __restrict__ embeds,
    const float* __restrict__ w_ih_f, const float* __restrict__ b_f,
    const float* __restrict__ w_ih_b, const float* __restrict__ b_b,
    float* __restrict__ xg) {
  int dir = blockIdx.z;
  const float* W = dir ? w_ih_b : w_ih_f;
  const float* B = dir ? b_b : b_f;
  float* out = xg + (size_t)dir * SEQ * G4H;
  int j0 = blockIdx.x * 64, t0 = blockIdx.y * 64;
  __shared__ float As[64][65];
  __shared__ float Bs[64][65];
  int tid = threadIdx.x;
  int ty = tid >> 4, tx = tid & 15;
  float acc[4][4] = {};
  for (int kc = 0; kc < EMB; kc += 64) {
#pragma unroll
    for (int i = 0; i < 4; ++i) {
      int fi = tid * 4 + i;
      int r = fi >> 4, c4 = fi & 15;
      float4 a = *(const float4*)&embeds[(size_t)(t0 + r) * EMB + kc + c4 * 4];
      As[r][c4 * 4 + 0] = a.x; As[r][c4 * 4 + 1] = a.y;
      As[r][c4 * 4 + 2] = a.z; As[r][c4 * 4 + 3] = a.w;
      float4 b = *(const float4*)&W[(size_t)(j0 + r) * EMB + kc + c4 * 4];
      Bs[r][c4 * 4 + 0] = b.x; Bs[r][c4 * 4 + 1] = b.y;
      Bs[r][c4 * 4 + 2] = b.z; Bs[r][c4 * 4 + 3] = b.w;
    }
    __syncthreads();
#pragma unroll 8
    for (int kk = 0; kk < 64; ++kk) {
      float a[4], b[4];
#pragma unroll
      for (int i = 0; i < 4; ++i) a[i] = As[ty * 4 + i][kk];
#pragma unroll
      for (int i = 0; i < 4; ++i) b[i] = Bs[tx * 4 + i][kk];
#pragma unroll
      for (int i = 0; i < 4; ++i)
#pragma unroll
        for (int j = 0; j < 4; ++j) acc[i][j] = fmaf(a[i], b[j], acc[i][j]);
    }
    __syncthreads();
  }
#pragma unroll
  for (int i = 0; i < 4; ++i)
#pragma unroll
    for (int j = 0; j < 4; ++j)
      out[(size_t)(t0 + ty * 4 + i) * G4H + j0 + tx * 4 + j] = acc[i][j] + B[j0 + tx * 4 + j];
}

// -------- kernel 3: LSTM scan, flag-signaled L2 hand-off (fast path) ---------
// Grid 1024 x 64thr; workers have b%8 in {0,1}: dir = b%8, Wk = b>>3 in [0,128).
// Fast path (same-XCD, elected): producers plain-store h to hb_fast (write-
// through -> shared L2), s_waitcnt, then ONE lane-0 atomic_add(+1, RELEASE,
// WORKGROUP) on flags[dir][t] (executes at the shared TCC; R7 proved fresh).
// Consumers poll flags with ONE lane-0 atomic_add(+0, ACQUIRE) per round until
// >=128, then plain-load h: each step's address is never touched before ->
// L1 cold miss -> guaranteed-fresh L2 hit (the R8 stale-L1 trap cannot occur
// on a once-read address). Bounded tries + sticky fallback to the proven
// agent/L3 sentinel poll on hb_safe (always also written) -> no deadlock.
__global__ __launch_bounds__(64) void lstm_scan(
    const float* __restrict__ w_hh_f, const float* __restrict__ w_hh_b,
    const float* __restrict__ xg, unsigned* __restrict__ hb_fast_base,
    unsigned* __restrict__ hb_safe_base, unsigned* __restrict__ xcdtab,
    unsigned* __restrict__ flags, int force_slow) {
  int b = blockIdx.x;
  int sel = b & 7;
  if (sel >= 2) return;  // non-worker block
  int dir = sel;
  int Wk = b >> 3;  // 0..127
  const float* W = dir ? w_hh_b : w_hh_f;
  const float* xgd = xg + (size_t)dir * SEQ * G4H;
  unsigned* hb_fast = hb_fast_base + (size_t)dir * SEQ * HID;
  unsigned* hb_safe = hb_safe_base + (size_t)dir * SEQ * HID;
  unsigned* flg = flags + (size_t)dir * SEQ;

  int lane = threadIdx.x;  // 0..63
  const int hh = lane & 3;
  const int k0 = 4 * Wk;

  // publish my XCD id (HW_REG_XCC_ID = hwreg 20), bits [3:0]
  int my_xcd = (int)(__builtin_amdgcn_s_getreg(20 | (31 << 11)) & 0xFu);
  if (lane == 0)
    __hip_atomic_store(&xcdtab[dir * 128 + Wk], (unsigned)my_xcd,
                       __ATOMIC_RELAXED, __HIP_MEMORY_SCOPE_AGENT);

  // stage W slice in LDS (overlaps other workers' publishing)
  __shared__ float4 Wl[16 * 128];  // f4 idx = r*128 + hf*64 + l
  for (int idx = lane; idx < 16 * 128; idx += 64) {
    int r = idx >> 7, c4 = idx & 127;
    int gr = 512 * (r >> 2) + k0 + (r & 3);
    Wl[idx] = *(const float4*)&W[(size_t)gr * HID + 4 * c4];
  }
  __syncthreads();

  // election read-back: fast only if all 128 producers of my dir on my XCD
  bool same = false;
  if (!force_slow) {
    bool ok = true;
#pragma unroll
    for (int pp = 0; pp < 2; ++pp) {
      int p = lane + 64 * pp;
      unsigned v = 0xFFFFFFFFu;
      for (int tries = 0; tries < (1 << 15); ++tries) {
        v = __hip_atomic_load(&xcdtab[dir * 128 + p], __ATOMIC_RELAXED,
                              __HIP_MEMORY_SCOPE_AGENT);
        if (v != 0xFFFFFFFFu) break;
        __builtin_amdgcn_s_sleep(4);
      }
      ok &= (v == (unsigned)my_xcd);
    }
    same = __all((int)ok);
  }

  float cst = 0.f;  // cell state for h[k0+hh] (redundant across 16-lane groups)

  for (int t = 0; t < SEQ; ++t) {
    int tt = dir ? (SEQ - 1 - t) : t;

    // xg contributions for my hh's 4 gates (issued early; overlaps the poll)
    const float* xrow = xgd + (size_t)tt * G4H + k0 + hh;
    float xv0 = xrow[0], xv1 = xrow[512], xv2 = xrow[1024], xv3 = xrow[1536];

    // obtain h_prev: lane needs cols {4l..4l+3} and {256+4l..256+4l+3}
    float4 h0, h1;
    if (t == 0) {
      h0 = make_float4(0.f, 0.f, 0.f, 0.f);
      h1 = make_float4(0.f, 0.f, 0.f, 0.f);
    } else {
      int pt = dir ? (tt + 1) : (tt - 1);
      unsigned w0, w1, w2, w3, w4, w5, w6, w7;
      bool got = false;
      if (same) {
        // flag poll: 1 RMW per wave per round, at the shared L2
        int bound = (t == 1) ? (1 << 17) : (1 << 12);
        for (int tries = 0; tries < bound; ++tries) {
          unsigned f = 0;
          if (lane == 0)
            f = __hip_atomic_fetch_add(&flg[pt], 0u, __ATOMIC_ACQUIRE,
                                       __HIP_MEMORY_SCOPE_WORKGROUP);
          f = __shfl(f, 0);
          if (f >= 128u) { got = true; break; }
        }
        if (!got) same = false;  // sticky fallback
      }
      if (got) {
        // plain loads: first touch of this address -> L1 miss -> fresh L2 hit
        const u4v* srcF = (const u4v*)(hb_fast + (size_t)pt * HID + 4 * lane);
        u4v a = srcF[0];
        u4v c = srcF[64];  // +256 dwords = +1024 B
        w0 = a.x; w1 = a.y; w2 = a.z; w3 = a.w;
        w4 = c.x; w5 = c.y; w6 = c.z; w7 = c.w;
      } else {
        // proven agent/L3 sentinel poll on hb_safe
        unsigned* src = hb_safe + (size_t)pt * HID + 4 * lane;
        for (;;) {
          u4v a, c;
          asm volatile(
              "global_load_dwordx4 %0, %2, off sc0 sc1\n\t"
              "global_load_dwordx4 %1, %2, off offset:1024 sc0 sc1\n\t"
              "s_waitcnt vmcnt(0)"
              : "=&v"(a), "=&v"(c)
              : "v"(src)
              : "memory");
          w0 = a.x; w1 = a.y; w2 = a.z; w3 = a.w;
          w4 = c.x; w5 = c.y; w6 = c.z; w7 = c.w;
          bool ok = (w0 != SENT) & (w1 != SENT) & (w2 != SENT) & (w3 != SENT) &
                    (w4 != SENT) & (w5 != SENT) & (w6 != SENT) & (w7 != SENT);
          if (__all((int)ok)) break;
          __builtin_amdgcn_s_sleep(1);
        }
      }
      h0.x = __uint_as_float(w0); h0.y = __uint_as_float(w1);
      h0.z = __uint_as_float(w2); h0.w = __uint_as_float(w3);
      h1.x = __uint_as_float(w4); h1.y = __uint_as_float(w5);
      h1.z = __uint_as_float(w6); h1.w = __uint_as_float(w7);
    }

    // matvec partials: acc[r] = sum over my 8 cols of W[r][c]*h[c]
    float acc[16];
#pragma unroll
    for (int r = 0; r < 16; ++r) {
      float4 wa = Wl[r * 128 + lane];
      float4 wc = Wl[r * 128 + 64 + lane];
      float a_ = wa.x * h0.x;
      a_ = fmaf(wa.y, h0.y, a_);
      a_ = fmaf(wa.z, h0.z, a_);
      a_ = fmaf(wa.w, h0.w, a_);
      a_ = fmaf(wc.x, h1.x, a_);
      a_ = fmaf(wc.y, h1.y, a_);
      a_ = fmaf(wc.z, h1.z, a_);
      a_ = fmaf(wc.w, h1.w, a_);
      acc[r] = a_;
    }

    // log-fold butterfly: 17 shfls; ends with lane holding row (lane&15)
    float v8[8];
    {
      int b0 = lane & 1;
#pragma unroll
      for (int j = 0; j < 8; ++j) {
        float mine = b0 ? acc[2 * j + 1] : acc[2 * j];
        float oth  = b0 ? acc[2 * j] : acc[2 * j + 1];
        v8[j] = mine + __shfl_xor(oth, 1);
      }
    }
    float v4[4];
    {
      int b1 = (lane >> 1) & 1;
#pragma unroll
      for (int j = 0; j < 4; ++j) {
        float mine = b1 ? v8[2 * j + 1] : v8[2 * j];
        float oth  = b1 ? v8[2 * j] : v8[2 * j + 1];
        v4[j] = mine + __shfl_xor(oth, 2);
      }
    }
    float v2[2];
    {
      int b2 = (lane >> 2) & 1;
#pragma unroll
      for (int j = 0; j < 2; ++j) {
        float mine = b2 ? v4[2 * j + 1] : v4[2 * j];
        float oth  = b2 ? v4[2 * j] : v4[2 * j + 1];
        v2[j] = mine + __shfl_xor(oth, 4);
      }
    }
    float v1;
    {
      int b3 = (lane >> 3) & 1;
      float mine = b3 ? v2[1] : v2[0];
      float oth  = b3 ? v2[0] : v2[1];
      v1 = mine + __shfl_xor(oth, 8);
      v1 += __shfl_xor(v1, 16);
      v1 += __shfl_xor(v1, 32);
    }

    // gather the 4 gate sums for my hh (rows 4g+hh live in lanes 4g+hh)
    float si = __shfl(v1, hh + 0)  + xv0;
    float sf = __shfl(v1, hh + 4)  + xv1;
    float sg = __shfl(v1, hh + 8)  + xv2;
    float so = __shfl(v1, hh + 12) + xv3;

    float iv = sigmoidf_(si), fv = sigmoidf_(sf), gv = tanhf_(sg), ov = sigmoidf_(so);
    cst = fv * cst + iv * gv;
    float h = ov * tanhf_(cst);
    unsigned hbits = __float_as_uint(h);
    if (lane < 4) {  // lane == hh here
      // plain write-through store -> local L2 (fast consumers)
      hb_fast[(size_t)tt * HID + k0 + lane] = hbits;
      // agent store -> L3 (fallback consumers + out_gemm)
      __hip_atomic_store(hb_safe + (size_t)tt * HID + k0 + lane, hbits,
                         __ATOMIC_RELAXED, __HIP_MEMORY_SCOPE_AGENT);
    }
    asm volatile("s_waitcnt vmcnt(0)" ::: "memory");  // h visible before flag
    if (lane == 0)
      __hip_atomic_fetch_add(&flg[tt], 1u, __ATOMIC_RELEASE,
                             __HIP_MEMORY_SCOPE_WORKGROUP);
  }
}

// ---------------- kernel 4: logits = h_cat @ w_out^T + b_out -----------------
__global__ __launch_bounds__(256) void out_gemm(
    const unsigned* __restrict__ hbuf, const float* __restrict__ w_out,
    const float* __restrict__ b_out, float* __restrict__ out) {
  int j0 = blockIdx.x * 128, t0 = blockIdx.y * 64;
  __shared__ float hs[64][65];
  __shared__ float ws_[128][65];
  int tid = threadIdx.x;
  int ti = tid & 15, ji = tid >> 4;
  float acc[4][8] = {};
  const float* hf = (const float*)hbuf;
  for (int kc = 0; kc < 1024; kc += 64) {
    const float* hsrc = (kc < 512) ? hf : (hf + (size_t)SEQ * HID);
    int kb = kc & 511;
#pragma unroll
    for (int i = 0; i < 4; ++i) {
      int fi = tid * 4 + i;
      int r = fi >> 4, c4 = fi & 15;
      float4 v = *(const float4*)&hsrc[(size_t)(t0 + r) * HID + kb + c4 * 4];
      hs[r][c4 * 4 + 0] = v.x; hs[r][c4 * 4 + 1] = v.y;
      hs[r][c4 * 4 + 2] = v.z; hs[r][c4 * 4 + 3] = v.w;
    }
#pragma unroll
    for (int i = 0; i < 8; ++i) {
      int fi = tid * 8 + i;
      int r = fi >> 4, c4 = fi & 15;
      float4 v = *(const float4*)&w_out[(size_t)(j0 + r) * 1024 + kc + c4 * 4];
      ws_[r][c4 * 4 + 0] = v.x; ws_[r][c4 * 4 + 1] = v.y;
      ws_[r][c4 * 4 + 2] = v.z; ws_[r][c4 * 4 + 3] = v.w;
    }
    __syncthreads();
#pragma unroll 4
    for (int kk = 0; kk < 64; ++kk) {
      float a[4], b[8];
#pragma unroll
      for (int x = 0; x < 4; ++x) a[x] = hs[ti * 4 + x][kk];
#pragma unroll
      for (int y = 0; y < 8; ++y) b[y] = ws_[ji * 8 + y][kk];
#pragma unroll
      for (int x = 0; x < 4; ++x)
#pragma unroll
        for (int y = 0; y < 8; ++y) acc[x][y] = fmaf(a[x], b[y], acc[x][y]);
    }
    __syncthreads();
  }
#pragma unroll
  for (int x = 0; x < 4; ++x)
#pragma unroll
    for (int y = 0; y < 8; ++y)
      out[(size_t)(t0 + ti * 4 + x) * TAGS + j0 + ji * 8 + y] = acc[x][y] + b_out[j0 + ji * 8 + y];
}

// ---------------- kernel 5: row-wise log_softmax in place --------------------
__global__ __launch_bounds__(256) void logsoftmax(float* __restrict__ out) {
  int t = blockIdx.x;
  float* row = out + (size_t)t * TAGS;
  int tid = threadIdx.x;
  float a = row[tid], b = row[tid + 256];
  float m = fmaxf(a, b);
  m = fmaxf(m, __shfl_xor(m, 1));
  m = fmaxf(m, __shfl_xor(m, 2));
  m = fmaxf(m, __shfl_xor(m, 4));
  m = fmaxf(m, __shfl_xor(m, 8));
  m = fmaxf(m, __shfl_xor(m, 16));
  m = fmaxf(m, __shfl_xor(m, 32));
  __shared__ float redm[4];
  __shared__ float reds[4];
  int wv = tid >> 6;
  if ((tid & 63) == 0) redm[wv] = m;
  __syncthreads();
  m = fmaxf(fmaxf(redm[0], redm[1]), fmaxf(redm[2], redm[3]));
  float s = __expf(a - m) + __expf(b - m);
  s += __shfl_xor(s, 1);
  s += __shfl_xor(s, 2);
  s += __shfl_xor(s, 4);
  s += __shfl_xor(s, 8);
  s += __shfl_xor(s, 16);
  s += __shfl_xor(s, 32);
  if ((tid & 63) == 0) reds[wv] = s;
  __syncthreads();
  s = reds[0] + reds[1] + reds[2] + reds[3];
  float ls = m + __logf(s);
  row[tid] = a - ls;
  row[tid + 256] = b - ls;
}

extern "C" void kernel_launch(void* const* d_in, const int* in_sizes, int n_in,
                              void* d_out, int out_size, void* d_ws, size_t ws_size,
                              hipStream_t stream) {
  (void)in_sizes; (void)n_in; (void)out_size;
  const float* emb    = (const float*)d_in[0];
  const float* w_ih_f = (const float*)d_in[1];
  const float* w_hh_f = (const float*)d_in[2];
  const float* b_f    = (const float*)d_in[3];
  const float* w_ih_b = (const float*)d_in[4];
  const float* w_hh_b = (const float*)d_in[5];
  const float* b_b    = (const float*)d_in[6];
  const float* w_out  = (const float*)d_in[7];
  const float* b_out  = (const float*)d_in[8];
  const int*   ids    = (const int*)d_in[9];
  const int*   seg    = (const int*)d_in[10];
  float* out = (float*)d_out;

  char* ws = (char*)d_ws;
  float*    embeds  = (float*)ws;                                  // 8 MB
  float*    xg      = (float*)(ws + (8ll << 20));                  // 128 MB
  unsigned* hb_safe = (unsigned*)(ws + (136ll << 20));             // 32 MB
  size_t need = (200ll << 20);
  int force_slow = (ws_size < need) ? 1 : 0;
  unsigned* hb_fast = force_slow ? hb_safe
                                 : (unsigned*)(ws + (168ll << 20));  // 32 MB
  // election table + flags live in d_out scratch (overwritten by out_gemm)
  unsigned* xcdtab = (unsigned*)d_out;            // 256 words
  unsigned* flags  = (unsigned*)d_out + 256;      // 2*SEQ words (64 KB)

  init_sentinel<<<2048, 256, 0, stream>>>(hb_safe, 2 * SEQ * HID,
                                          xcdtab, 256, flags, 2 * SEQ);
  embed_pool<<<SEQ, 256, 0, stream>>>(emb, ids, seg, embeds);
  dim3 g2(G4H / 64, SEQ / 64, 2);
  xg_gemm<<<g2, 256, 0, stream>>>(embeds, w_ih_f, b_f, w_ih_b, b_b, xg);
  lstm_scan<<<1024, 64, 0, stream>>>(w_hh_f, w_hh_b, xg, hb_fast, hb_safe,
                                     xcdtab, flags, force_slow);
  dim3 g4(TAGS / 128, SEQ / 64);
  out_gemm<<<g4, 256, 0, stream>>>(hb_safe, w_out, b_out, out);
  logsoftmax<<<SEQ, 256, 0, stream>>>(out);
}

// Round 10
// 15542.244 us; speedup vs baseline: 2.7940x; 2.7940x over previous
//
#include <hip/hip_runtime.h>
#include <hip/hip_bf16.h>

#define VOCAB 200000
#define EMB 256
#define HID 512
#define SEQ 8192
#define TOK 32768
#define TAGS 512
#define G4H 2048  // 4*HID

#define SENT 0x7FBFFFFFu  // NaN payload sentinel; real h is always finite

typedef unsigned u4v __attribute__((ext_vector_type(4)));

__device__ __forceinline__ float sigmoidf_(float x) { return 1.0f / (1.0f + __expf(-x)); }
__device__ __forceinline__ float tanhf_(float x) { return 1.0f - 2.0f / (1.0f + __expf(2.0f * x)); }

// ------------- kernel 0: init (both h buffers + election table) --------------
__global__ void init_sentinel(unsigned* __restrict__ hbuf, int n,
                              unsigned* __restrict__ tab, int ntab) {
  int i = blockIdx.x * blockDim.x + threadIdx.x;
  int stride = gridDim.x * blockDim.x;
  for (int k = i; k < n; k += stride) hbuf[k] = SENT;
  for (int k = i; k < ntab; k += stride) tab[k] = 0xFFFFFFFFu;
}

// ---------------- kernel 1: embedding bag (sum pool per sorted segment) ------
__global__ __launch_bounds__(256) void embed_pool(
    const float* __restrict__ emb, const int* __restrict__ ids,
    const int* __restrict__ seg, float* __restrict__ out) {
  int s = blockIdx.x;
  int d = threadIdx.x;  // 256 = EMB
  int lo = 0, hi = TOK;
  while (lo < hi) { int m = (lo + hi) >> 1; if (seg[m] < s) lo = m + 1; else hi = m; }
  int start = lo;
  hi = TOK;
  while (lo < hi) { int m = (lo + hi) >> 1; if (seg[m] < s + 1) lo = m + 1; else hi = m; }
  int end = lo;
  float acc = 0.f;
  for (int tkn = start; tkn < end; ++tkn) {
    acc += emb[(long)ids[tkn] * EMB + d];
  }
  out[s * EMB + d] = acc;
}

// ---------------- kernel 2: xg = embeds @ w_ih^T + b  (both dirs) ------------
__global__ __launch_bounds__(256) void xg_gemm(
    const float* __restrict__ embeds,
    const float* __restrict__ w_ih_f, const float* __restrict__ b_f,
    const float* __restrict__ w_ih_b, const float* __restrict__ b_b,
    float* __restrict__ xg) {
  int dir = blockIdx.z;
  const float* W = dir ? w_ih_b : w_ih_f;
  const float* B = dir ? b_b : b_f;
  float* out = xg + (size_t)dir * SEQ * G4H;
  int j0 = blockIdx.x * 64, t0 = blockIdx.y * 64;
  __shared__ float As[64][65];
  __shared__ float Bs[64][65];
  int tid = threadIdx.x;
  int ty = tid >> 4, tx = tid & 15;
  float acc[4][4] = {};
  for (int kc = 0; kc < EMB; kc += 64) {
#pragma unroll
    for (int i = 0; i < 4; ++i) {
      int fi = tid * 4 + i;
      int r = fi >> 4, c4 = fi & 15;
      float4 a = *(const float4*)&embeds[(size_t)(t0 + r) * EMB + kc + c4 * 4];
      As[r][c4 * 4 + 0] = a.x; As[r][c4 * 4 + 1] = a.y;
      As[r][c4 * 4 + 2] = a.z; As[r][c4 * 4 + 3] = a.w;
      float4 b = *(const float4*)&W[(size_t)(j0 + r) * EMB + kc + c4 * 4];
      Bs[r][c4 * 4 + 0] = b.x; Bs[r][c4 * 4 + 1] = b.y;
      Bs[r][c4 * 4 + 2] = b.z; Bs[r][c4 * 4 + 3] = b.w;
    }
    __syncthreads();
#pragma unroll 8
    for (int kk = 0; kk < 64; ++kk) {
      float a[4], b[4];
#pragma unroll
      for (int i = 0; i < 4; ++i) a[i] = As[ty * 4 + i][kk];
#pragma unroll
      for (int i = 0; i < 4; ++i) b[i] = Bs[tx * 4 + i][kk];
#pragma unroll
      for (int i = 0; i < 4; ++i)
#pragma unroll
        for (int j = 0; j < 4; ++j) acc[i][j] = fmaf(a[i], b[j], acc[i][j]);
    }
    __syncthreads();
  }
#pragma unroll
  for (int i = 0; i < 4; ++i)
#pragma unroll
    for (int j = 0; j < 4; ++j)
      out[(size_t)(t0 + ty * 4 + i) * G4H + j0 + tx * 4 + j] = acc[i][j] + B[j0 + tx * 4 + j];
}

// -------- kernel 3: LSTM scan, Device-scope (sc1) L2 sentinel poll -----------
// Structure = round 5/8 (proven). Cache-scope model from R5/R7/R8/R9 evidence:
//   sc0      (SE scope)     : L1-served -> stale on re-poll   (R8)
//   sc0 sc1  (System scope) : bypass L1+L2 -> L3, ~800cy      (R5)
//   atomics  (any scope)    : fresh at L2 but RMW-serialized  (R7/R9)
//   sc1      (Device scope) : bypass L1, serviced at shared L2  <- THIS ROUND
// Producers plain-store h to hb_fast (write-through -> local L2, line stays
// resident) + agent-store to hb_safe (L3; fallback & out_gemm). Elected
// same-XCD consumers sentinel-poll hb_fast with sc1 loads; bounded tries with
// sticky fallback to the proven hb_safe L3 poll -> hang-proof.
__global__ __launch_bounds__(64) void lstm_scan(
    const float* __restrict__ w_hh_f, const float* __restrict__ w_hh_b,
    const float* __restrict__ xg, unsigned* __restrict__ hb_fast_base,
    unsigned* __restrict__ hb_safe_base, unsigned* __restrict__ xcdtab,
    int force_slow) {
  int b = blockIdx.x;
  int sel = b & 7;
  if (sel >= 2) return;  // non-worker block
  int dir = sel;
  int Wk = b >> 3;  // 0..127
  const float* W = dir ? w_hh_b : w_hh_f;
  const float* xgd = xg + (size_t)dir * SEQ * G4H;
  unsigned* hb_fast = hb_fast_base + (size_t)dir * SEQ * HID;
  unsigned* hb_safe = hb_safe_base + (size_t)dir * SEQ * HID;

  int lane = threadIdx.x;  // 0..63
  const int hh = lane & 3;
  const int k0 = 4 * Wk;

  // publish my XCD id (HW_REG_XCC_ID = hwreg 20)
  int my_xcd = (int)(__builtin_amdgcn_s_getreg(20 | (31 << 11)) & 0xFu);
  if (lane == 0)
    __hip_atomic_store(&xcdtab[dir * 128 + Wk], (unsigned)my_xcd,
                       __ATOMIC_RELAXED, __HIP_MEMORY_SCOPE_AGENT);

  // stage W slice in LDS (overlaps other workers' publishing)
  __shared__ float4 Wl[16 * 128];  // f4 idx = r*128 + hf*64 + l
  for (int idx = lane; idx < 16 * 128; idx += 64) {
    int r = idx >> 7, c4 = idx & 127;
    int gr = 512 * (r >> 2) + k0 + (r & 3);
    Wl[idx] = *(const float4*)&W[(size_t)gr * HID + 4 * c4];
  }
  __syncthreads();

  // election read-back: fast only if all 128 producers of my dir on my XCD
  bool same = false;
  if (!force_slow) {
    bool ok = true;
#pragma unroll
    for (int pp = 0; pp < 2; ++pp) {
      int p = lane + 64 * pp;
      unsigned v = 0xFFFFFFFFu;
      for (int tries = 0; tries < (1 << 15); ++tries) {
        v = __hip_atomic_load(&xcdtab[dir * 128 + p], __ATOMIC_RELAXED,
                              __HIP_MEMORY_SCOPE_AGENT);
        if (v != 0xFFFFFFFFu) break;
        __builtin_amdgcn_s_sleep(4);
      }
      ok &= (v == (unsigned)my_xcd);
    }
    same = __all((int)ok);
  }

  float cst = 0.f;  // cell state for h[k0+hh] (redundant across 16-lane groups)

  for (int t = 0; t < SEQ; ++t) {
    int tt = dir ? (SEQ - 1 - t) : t;

    // xg contributions for my hh's 4 gates (issued early; overlaps the poll)
    const float* xrow = xgd + (size_t)tt * G4H + k0 + hh;
    float xv0 = xrow[0], xv1 = xrow[512], xv2 = xrow[1024], xv3 = xrow[1536];

    // obtain h_prev: lane needs cols {4l..4l+3} and {256+4l..256+4l+3}
    float4 h0, h1;
    if (t == 0) {
      h0 = make_float4(0.f, 0.f, 0.f, 0.f);
      h1 = make_float4(0.f, 0.f, 0.f, 0.f);
    } else {
      int pt = dir ? (tt + 1) : (tt - 1);
      unsigned w0, w1, w2, w3, w4, w5, w6, w7;
      bool got = false;
      if (same) {
        // Device-scope (sc1) sentinel poll on hb_fast: L1-bypass, L2-served
        unsigned* srcF = hb_fast + (size_t)pt * HID + 4 * lane;
        int bound = (t == 1) ? (1 << 14) : 64;
        for (int tries = 0; tries < bound && !got; ++tries) {
          u4v a, c;
          asm volatile(
              "global_load_dwordx4 %0, %2, off sc1\n\t"
              "global_load_dwordx4 %1, %2, off offset:1024 sc1\n\t"
              "s_waitcnt vmcnt(0)"
              : "=&v"(a), "=&v"(c)
              : "v"(srcF)
              : "memory");
          w0 = a.x; w1 = a.y; w2 = a.z; w3 = a.w;
          w4 = c.x; w5 = c.y; w6 = c.z; w7 = c.w;
          bool ok = (w0 != SENT) & (w1 != SENT) & (w2 != SENT) & (w3 != SENT) &
                    (w4 != SENT) & (w5 != SENT) & (w6 != SENT) & (w7 != SENT);
          got = __all((int)ok);
          if (!got) __builtin_amdgcn_s_sleep(1);
        }
        if (!got) same = false;  // sticky: Device-scope model falsified
      }
      if (!got) {
        // proven System-scope (L3) sentinel poll on hb_safe
        unsigned* src = hb_safe + (size_t)pt * HID + 4 * lane;
        for (;;) {
          u4v a, c;
          asm volatile(
              "global_load_dwordx4 %0, %2, off sc0 sc1\n\t"
              "global_load_dwordx4 %1, %2, off offset:1024 sc0 sc1\n\t"
              "s_waitcnt vmcnt(0)"
              : "=&v"(a), "=&v"(c)
              : "v"(src)
              : "memory");
          w0 = a.x; w1 = a.y; w2 = a.z; w3 = a.w;
          w4 = c.x; w5 = c.y; w6 = c.z; w7 = c.w;
          bool ok = (w0 != SENT) & (w1 != SENT) & (w2 != SENT) & (w3 != SENT) &
                    (w4 != SENT) & (w5 != SENT) & (w6 != SENT) & (w7 != SENT);
          if (__all((int)ok)) break;
          __builtin_amdgcn_s_sleep(1);
        }
      }
      h0.x = __uint_as_float(w0); h0.y = __uint_as_float(w1);
      h0.z = __uint_as_float(w2); h0.w = __uint_as_float(w3);
      h1.x = __uint_as_float(w4); h1.y = __uint_as_float(w5);
      h1.z = __uint_as_float(w6); h1.w = __uint_as_float(w7);
    }

    // matvec partials: acc[r] = sum over my 8 cols of W[r][c]*h[c]
    float acc[16];
#pragma unroll
    for (int r = 0; r < 16; ++r) {
      float4 wa = Wl[r * 128 + lane];
      float4 wc = Wl[r * 128 + 64 + lane];
      float a_ = wa.x * h0.x;
      a_ = fmaf(wa.y, h0.y, a_);
      a_ = fmaf(wa.z, h0.z, a_);
      a_ = fmaf(wa.w, h0.w, a_);
      a_ = fmaf(wc.x, h1.x, a_);
      a_ = fmaf(wc.y, h1.y, a_);
      a_ = fmaf(wc.z, h1.z, a_);
      a_ = fmaf(wc.w, h1.w, a_);
      acc[r] = a_;
    }

    // log-fold butterfly: 17 shfls; ends with lane holding row (lane&15)
    float v8[8];
    {
      int b0 = lane & 1;
#pragma unroll
      for (int j = 0; j < 8; ++j) {
        float mine = b0 ? acc[2 * j + 1] : acc[2 * j];
        float oth  = b0 ? acc[2 * j] : acc[2 * j + 1];
        v8[j] = mine + __shfl_xor(oth, 1);
      }
    }
    float v4[4];
    {
      int b1 = (lane >> 1) & 1;
#pragma unroll
      for (int j = 0; j < 4; ++j) {
        float mine = b1 ? v8[2 * j + 1] : v8[2 * j];
        float oth  = b1 ? v8[2 * j] : v8[2 * j + 1];
        v4[j] = mine + __shfl_xor(oth, 2);
      }
    }
    float v2[2];
    {
      int b2 = (lane >> 2) & 1;
#pragma unroll
      for (int j = 0; j < 2; ++j) {
        float mine = b2 ? v4[2 * j + 1] : v4[2 * j];
        float oth  = b2 ? v4[2 * j] : v4[2 * j + 1];
        v2[j] = mine + __shfl_xor(oth, 4);
      }
    }
    float v1;
    {
      int b3 = (lane >> 3) & 1;
      float mine = b3 ? v2[1] : v2[0];
      float oth  = b3 ? v2[0] : v2[1];
      v1 = mine + __shfl_xor(oth, 8);
      v1 += __shfl_xor(v1, 16);
      v1 += __shfl_xor(v1, 32);
    }

    // gather the 4 gate sums for my hh (rows 4g+hh live in lanes 4g+hh)
    float si = __shfl(v1, hh + 0)  + xv0;
    float sf = __shfl(v1, hh + 4)  + xv1;
    float sg = __shfl(v1, hh + 8)  + xv2;
    float so = __shfl(v1, hh + 12) + xv3;

    float iv = sigmoidf_(si), fv = sigmoidf_(sf), gv = tanhf_(sg), ov = sigmoidf_(so);
    cst = fv * cst + iv * gv;
    float h = ov * tanhf_(cst);
    unsigned hbits = __float_as_uint(h);
    if (lane < 4) {  // lane == hh here
      if (!force_slow)  // plain write-through store -> local L2 (fast readers)
        hb_fast[(size_t)tt * HID + k0 + lane] = hbits;
      __hip_atomic_store(hb_safe + (size_t)tt * HID + k0 + lane, hbits,
                         __ATOMIC_RELAXED, __HIP_MEMORY_SCOPE_AGENT);
    }
  }
}

// ---------------- kernel 4: logits = h_cat @ w_out^T + b_out -----------------
__global__ __launch_bounds__(256) void out_gemm(
    const unsigned* __restrict__ hbuf, const float* __restrict__ w_out,
    const float* __restrict__ b_out, float* __restrict__ out) {
  int j0 = blockIdx.x * 128, t0 = blockIdx.y * 64;
  __shared__ float hs[64][65];
  __shared__ float ws_[128][65];
  int tid = threadIdx.x;
  int ti = tid & 15, ji = tid >> 4;
  float acc[4][8] = {};
  const float* hf = (const float*)hbuf;
  for (int kc = 0; kc < 1024; kc += 64) {
    const float* hsrc = (kc < 512) ? hf : (hf + (size_t)SEQ * HID);
    int kb = kc & 511;
#pragma unroll
    for (int i = 0; i < 4; ++i) {
      int fi = tid * 4 + i;
      int r = fi >> 4, c4 = fi & 15;
      float4 v = *(const float4*)&hsrc[(size_t)(t0 + r) * HID + kb + c4 * 4];
      hs[r][c4 * 4 + 0] = v.x; hs[r][c4 * 4 + 1] = v.y;
      hs[r][c4 * 4 + 2] = v.z; hs[r][c4 * 4 + 3] = v.w;
    }
#pragma unroll
    for (int i = 0; i < 8; ++i) {
      int fi = tid * 8 + i;
      int r = fi >> 4, c4 = fi & 15;
      float4 v = *(const float4*)&w_out[(size_t)(j0 + r) * 1024 + kc + c4 * 4];
      ws_[r][c4 * 4 + 0] = v.x; ws_[r][c4 * 4 + 1] = v.y;
      ws_[r][c4 * 4 + 2] = v.z; ws_[r][c4 * 4 + 3] = v.w;
    }
    __syncthreads();
#pragma unroll 4
    for (int kk = 0; kk < 64; ++kk) {
      float a[4], b[8];
#pragma unroll
      for (int x = 0; x < 4; ++x) a[x] = hs[ti * 4 + x][kk];
#pragma unroll
      for (int y = 0; y < 8; ++y) b[y] = ws_[ji * 8 + y][kk];
#pragma unroll
      for (int x = 0; x < 4; ++x)
#pragma unroll
        for (int y = 0; y < 8; ++y) acc[x][y] = fmaf(a[x], b[y], acc[x][y]);
    }
    __syncthreads();
  }
#pragma unroll
  for (int x = 0; x < 4; ++x)
#pragma unroll
    for (int y = 0; y < 8; ++y)
      out[(size_t)(t0 + ti * 4 + x) * TAGS + j0 + ji * 8 + y] = acc[x][y] + b_out[j0 + ji * 8 + y];
}

// ---------------- kernel 5: row-wise log_softmax in place --------------------
__global__ __launch_bounds__(256) void logsoftmax(float* __restrict__ out) {
  int t = blockIdx.x;
  float* row = out + (size_t)t * TAGS;
  int tid = threadIdx.x;
  float a = row[tid], b = row[tid + 256];
  float m = fmaxf(a, b);
  m = fmaxf(m, __shfl_xor(m, 1));
  m = fmaxf(m, __shfl_xor(m, 2));
  m = fmaxf(m, __shfl_xor(m, 4));
  m = fmaxf(m, __shfl_xor(m, 8));
  m = fmaxf(m, __shfl_xor(m, 16));
  m = fmaxf(m, __shfl_xor(m, 32));
  __shared__ float redm[4];
  __shared__ float reds[4];
  int wv = tid >> 6;
  if ((tid & 63) == 0) redm[wv] = m;
  __syncthreads();
  m = fmaxf(fmaxf(redm[0], redm[1]), fmaxf(redm[2], redm[3]));
  float s = __expf(a - m) + __expf(b - m);
  s += __shfl_xor(s, 1);
  s += __shfl_xor(s, 2);
  s += __shfl_xor(s, 4);
  s += __shfl_xor(s, 8);
  s += __shfl_xor(s, 16);
  s += __shfl_xor(s, 32);
  if ((tid & 63) == 0) reds[wv] = s;
  __syncthreads();
  s = reds[0] + reds[1] + reds[2] + reds[3];
  float ls = m + __logf(s);
  row[tid] = a - ls;
  row[tid + 256] = b - ls;
}

extern "C" void kernel_launch(void* const* d_in, const int* in_sizes, int n_in,
                              void* d_out, int out_size, void* d_ws, size_t ws_size,
                              hipStream_t stream) {
  (void)in_sizes; (void)n_in; (void)out_size;
  const float* emb    = (const float*)d_in[0];
  const float* w_ih_f = (const float*)d_in[1];
  const float* w_hh_f = (const float*)d_in[2];
  const float* b_f    = (const float*)d_in[3];
  const float* w_ih_b = (const float*)d_in[4];
  const float* w_hh_b = (const float*)d_in[5];
  const float* b_b    = (const float*)d_in[6];
  const float* w_out  = (const float*)d_in[7];
  const float* b_out  = (const float*)d_in[8];
  const int*   ids    = (const int*)d_in[9];
  const int*   seg    = (const int*)d_in[10];
  float* out = (float*)d_out;

  char* ws = (char*)d_ws;
  float*    embeds  = (float*)ws;                                  // 8 MB
  float*    xg      = (float*)(ws + (8ll << 20));                  // 128 MB
  unsigned* hb_safe = (unsigned*)(ws + (136ll << 20));             // 32 MB
  size_t need = (200ll << 20);
  int force_slow = (ws_size < need) ? 1 : 0;
  unsigned* hb_fast = force_slow ? hb_safe
                                 : (unsigned*)(ws + (168ll << 20));  // 32 MB
  unsigned* xcdtab = (unsigned*)d_out;  // 256 words; overwritten by out_gemm

  // hb_safe and hb_fast are contiguous (136..200 MB): one sentinel sweep
  int hwords = (force_slow ? 1 : 2) * 2 * SEQ * HID;
  init_sentinel<<<2048, 256, 0, stream>>>(hb_safe, hwords, xcdtab, 256);
  embed_pool<<<SEQ, 256, 0, stream>>>(emb, ids, seg, embeds);
  dim3 g2(G4H / 64, SEQ / 64, 2);
  xg_gemm<<<g2, 256, 0, stream>>>(embeds, w_ih_f, b_f, w_ih_b, b_b, xg);
  lstm_scan<<<1024, 64, 0, stream>>>(w_hh_f, w_hh_b, xg, hb_fast, hb_safe,
                                     xcdtab, force_slow);
  dim3 g4(TAGS / 128, SEQ / 64);
  out_gemm<<<g4, 256, 0, stream>>>(hb_safe, w_out, b_out, out);
  logsoftmax<<<SEQ, 256, 0, stream>>>(out);
}

// Round 12
// 12820.711 us; speedup vs baseline: 3.3871x; 1.2123x over previous
//
#include <hip/hip_runtime.h>
#include <hip/hip_bf16.h>

#define VOCAB 200000
#define EMB 256
#define HID 512
#define SEQ 8192
#define TOK 32768
#define TAGS 512
#define G4H 2048  // 4*HID

#define SENT 0x7FBFFFFFu  // NaN payload sentinel; real h is always finite

typedef unsigned u4v __attribute__((ext_vector_type(4)));

__device__ __forceinline__ float sigmoidf_(float x) { return 1.0f / (1.0f + __expf(-x)); }
__device__ __forceinline__ float tanhf_(float x) { return 1.0f - 2.0f / (1.0f + __expf(2.0f * x)); }

// ------------- kernel 0: init (both h buffers + election table) --------------
__global__ void init_sentinel(unsigned* __restrict__ hbuf, int n,
                              unsigned* __restrict__ tab, int ntab) {
  int i = blockIdx.x * blockDim.x + threadIdx.x;
  int stride = gridDim.x * blockDim.x;
  for (int k = i; k < n; k += stride) hbuf[k] = SENT;
  for (int k = i; k < ntab; k += stride) tab[k] = 0xFFFFFFFFu;
}

// ---------------- kernel 1: embedding bag (sum pool per sorted segment) ------
__global__ __launch_bounds__(256) void embed_pool(
    const float* __restrict__ emb, const int* __restrict__ ids,
    const int* __restrict__ seg, float* __restrict__ out) {
  int s = blockIdx.x;
  int d = threadIdx.x;  // 256 = EMB
  int lo = 0, hi = TOK;
  while (lo < hi) { int m = (lo + hi) >> 1; if (seg[m] < s) lo = m + 1; else hi = m; }
  int start = lo;
  hi = TOK;
  while (lo < hi) { int m = (lo + hi) >> 1; if (seg[m] < s + 1) lo = m + 1; else hi = m; }
  int end = lo;
  float acc = 0.f;
  for (int tkn = start; tkn < end; ++tkn) {
    acc += emb[(long)ids[tkn] * EMB + d];
  }
  out[s * EMB + d] = acc;
}

// ---------------- kernel 2: xg = embeds @ w_ih^T + b  (both dirs) ------------
__global__ __launch_bounds__(256) void xg_gemm(
    const float* __restrict__ embeds,
    const float* __restrict__ w_ih_f, const float* __restrict__ b_f,
    const float* __restrict__ w_ih_b, const float* __restrict__ b_b,
    float* __restrict__ xg) {
  int dir = blockIdx.z;
  const float* W = dir ? w_ih_b : w_ih_f;
  const float* B = dir ? b_b : b_f;
  float* out = xg + (size_t)dir * SEQ * G4H;
  int j0 = blockIdx.x * 64, t0 = blockIdx.y * 64;
  __shared__ float As[64][65];
  __shared__ float Bs[64][65];
  int tid = threadIdx.x;
  int ty = tid >> 4, tx = tid & 15;
  float acc[4][4] = {};
  for (int kc = 0; kc < EMB; kc += 64) {
#pragma unroll
    for (int i = 0; i < 4; ++i) {
      int fi = tid * 4 + i;
      int r = fi >> 4, c4 = fi & 15;
      float4 a = *(const float4*)&embeds[(size_t)(t0 + r) * EMB + kc + c4 * 4];
      As[r][c4 * 4 + 0] = a.x; As[r][c4 * 4 + 1] = a.y;
      As[r][c4 * 4 + 2] = a.z; As[r][c4 * 4 + 3] = a.w;
      float4 b = *(const float4*)&W[(size_t)(j0 + r) * EMB + kc + c4 * 4];
      Bs[r][c4 * 4 + 0] = b.x; Bs[r][c4 * 4 + 1] = b.y;
      Bs[r][c4 * 4 + 2] = b.z; Bs[r][c4 * 4 + 3] = b.w;
    }
    __syncthreads();
#pragma unroll 8
    for (int kk = 0; kk < 64; ++kk) {
      float a[4], b[4];
#pragma unroll
      for (int i = 0; i < 4; ++i) a[i] = As[ty * 4 + i][kk];
#pragma unroll
      for (int i = 0; i < 4; ++i) b[i] = Bs[tx * 4 + i][kk];
#pragma unroll
      for (int i = 0; i < 4; ++i)
#pragma unroll
        for (int j = 0; j < 4; ++j) acc[i][j] = fmaf(a[i], b[j], acc[i][j]);
    }
    __syncthreads();
  }
#pragma unroll
  for (int i = 0; i < 4; ++i)
#pragma unroll
    for (int j = 0; j < 4; ++j)
      out[(size_t)(t0 + ty * 4 + i) * G4H + j0 + tx * 4 + j] = acc[i][j] + B[j0 + tx * 4 + j];
}

// -------- kernel 3: LSTM scan, sc1-L2 poll + latency-ordered dataflow --------
// Protocol = round 10 (proven). Dataflow = round 11 (A-E) with the rule-#18
// fix: the deferred waitcnt TIES the poll destination registers ("+v") and is
// followed by sched_barrier(0), so the register-only SENT check cannot be
// hoisted above the wait (R11's NaN: check ran on in-flight registers).
__global__ __launch_bounds__(64, 1) void lstm_scan(
    const float* __restrict__ w_hh_f, const float* __restrict__ w_hh_b,
    const float* __restrict__ xg, unsigned* __restrict__ hb_fast_base,
    unsigned* __restrict__ hb_safe_base, unsigned* __restrict__ xcdtab,
    int force_slow) {
  int b = blockIdx.x;
  int sel = b & 7;
  if (sel >= 2) return;  // non-worker block
  int dir = sel;
  int Wk = b >> 3;  // 0..127
  const float* W = dir ? w_hh_b : w_hh_f;
  const float* xgd = xg + (size_t)dir * SEQ * G4H;
  unsigned* hb_fast = hb_fast_base + (size_t)dir * SEQ * HID;
  unsigned* hb_safe = hb_safe_base + (size_t)dir * SEQ * HID;

  int lane = threadIdx.x;  // 0..63
  const int hh = lane & 3;
  const int k0 = 4 * Wk;

  // publish my XCD id (HW_REG_XCC_ID = hwreg 20)
  int my_xcd = (int)(__builtin_amdgcn_s_getreg(20 | (31 << 11)) & 0xFu);
  if (lane == 0)
    __hip_atomic_store(&xcdtab[dir * 128 + Wk], (unsigned)my_xcd,
                       __ATOMIC_RELAXED, __HIP_MEMORY_SCOPE_AGENT);

  // stage W slice in LDS (overlaps other workers' publishing)
  __shared__ float4 Wl[16 * 128];  // f4 idx = r*128 + hf*64 + l
  for (int idx = lane; idx < 16 * 128; idx += 64) {
    int r = idx >> 7, c4 = idx & 127;
    int gr = 512 * (r >> 2) + k0 + (r & 3);
    Wl[idx] = *(const float4*)&W[(size_t)gr * HID + 4 * c4];
  }
  __syncthreads();

  // election read-back: fast only if all 128 producers of my dir on my XCD
  bool same = false;
  if (!force_slow) {
    bool ok = true;
#pragma unroll
    for (int pp = 0; pp < 2; ++pp) {
      int p = lane + 64 * pp;
      unsigned v = 0xFFFFFFFFu;
      for (int tries = 0; tries < (1 << 15); ++tries) {
        v = __hip_atomic_load(&xcdtab[dir * 128 + p], __ATOMIC_RELAXED,
                              __HIP_MEMORY_SCOPE_AGENT);
        if (v != 0xFFFFFFFFu) break;
        __builtin_amdgcn_s_sleep(4);
      }
      ok &= (v == (unsigned)my_xcd);
    }
    same = __all((int)ok);
  }

  // prologue: xg for the first step (in registers at loop entry)
  int tt0 = dir ? (SEQ - 1) : 0;
  const float* xr0 = xgd + (size_t)tt0 * G4H + k0 + hh;
  float xv0 = xr0[0], xv1 = xr0[512], xv2 = xr0[1024], xv3 = xr0[1536];

  float cst = 0.f;  // cell state for h[k0+hh] (redundant across 16-lane groups)

  for (int t = 0; t < SEQ; ++t) {
    int tt = dir ? (SEQ - 1 - t) : t;
    int pt = dir ? (tt + 1) : (tt - 1);
    unsigned* srcF = hb_fast + (size_t)pt * HID + 4 * lane;

    // A. issue first fast-poll sample before anything else
    u4v pa, pc;
    bool fastpoll = (t > 0) && same;
    if (fastpoll) {
      asm volatile(
          "global_load_dwordx4 %0, %2, off sc1\n\t"
          "global_load_dwordx4 %1, %2, off offset:1024 sc1"
          : "=&v"(pa), "=&v"(pc)
          : "v"(srcF)
          : "memory");
    }

    // B. weight slice reads (LDS; independent of h; overlap poll RTT)
    float4 wl0[16], wl1[16];
#pragma unroll
    for (int r = 0; r < 16; ++r) {
      wl0[r] = Wl[r * 128 + lane];
      wl1[r] = Wl[r * 128 + 64 + lane];
    }

    // C. resolve h_prev
    float4 h0, h1;
    if (t == 0) {
      h0 = make_float4(0.f, 0.f, 0.f, 0.f);
      h1 = make_float4(0.f, 0.f, 0.f, 0.f);
    } else {
      unsigned w0, w1, w2, w3, w4, w5, w6, w7;
      bool got = false;
      if (fastpoll) {
        // rule-#18-safe deferred wait: tie poll regs + sched fence
        asm volatile("s_waitcnt vmcnt(0)" : "+v"(pa), "+v"(pc) :: "memory");
        __builtin_amdgcn_sched_barrier(0);
        w0 = pa.x; w1 = pa.y; w2 = pa.z; w3 = pa.w;
        w4 = pc.x; w5 = pc.y; w6 = pc.z; w7 = pc.w;
        bool ok = (w0 != SENT) & (w1 != SENT) & (w2 != SENT) & (w3 != SENT) &
                  (w4 != SENT) & (w5 != SENT) & (w6 != SENT) & (w7 != SENT);
        got = __all((int)ok);
        int bound = (t == 1) ? (1 << 14) : 256;
        for (int tries = 0; tries < bound && !got; ++tries) {
          u4v a, c;
          asm volatile(
              "global_load_dwordx4 %0, %2, off sc1\n\t"
              "global_load_dwordx4 %1, %2, off offset:1024 sc1\n\t"
              "s_waitcnt vmcnt(0)"
              : "=&v"(a), "=&v"(c)
              : "v"(srcF)
              : "memory");
          __builtin_amdgcn_sched_barrier(0);
          w0 = a.x; w1 = a.y; w2 = a.z; w3 = a.w;
          w4 = c.x; w5 = c.y; w6 = c.z; w7 = c.w;
          ok = (w0 != SENT) & (w1 != SENT) & (w2 != SENT) & (w3 != SENT) &
               (w4 != SENT) & (w5 != SENT) & (w6 != SENT) & (w7 != SENT);
          got = __all((int)ok);
        }
        if (!got) same = false;  // sticky: fall back permanently
      }
      if (!got) {
        // proven System-scope (L3) sentinel poll on hb_safe
        unsigned* src = hb_safe + (size_t)pt * HID + 4 * lane;
        for (;;) {
          u4v a, c;
          asm volatile(
              "global_load_dwordx4 %0, %2, off sc0 sc1\n\t"
              "global_load_dwordx4 %1, %2, off offset:1024 sc0 sc1\n\t"
              "s_waitcnt vmcnt(0)"
              : "=&v"(a), "=&v"(c)
              : "v"(src)
              : "memory");
          __builtin_amdgcn_sched_barrier(0);
          w0 = a.x; w1 = a.y; w2 = a.z; w3 = a.w;
          w4 = c.x; w5 = c.y; w6 = c.z; w7 = c.w;
          bool ok = (w0 != SENT) & (w1 != SENT) & (w2 != SENT) & (w3 != SENT) &
                    (w4 != SENT) & (w5 != SENT) & (w6 != SENT) & (w7 != SENT);
          if (__all((int)ok)) break;
          __builtin_amdgcn_s_sleep(1);
        }
      }
      h0.x = __uint_as_float(w0); h0.y = __uint_as_float(w1);
      h0.z = __uint_as_float(w2); h0.w = __uint_as_float(w3);
      h1.x = __uint_as_float(w4); h1.y = __uint_as_float(w5);
      h1.z = __uint_as_float(w6); h1.w = __uint_as_float(w7);
    }

    // D. prefetch next step's xg (outside every poll's vmcnt window)
    int tn = (t + 1 < SEQ) ? (t + 1) : t;
    int ttn = dir ? (SEQ - 1 - tn) : tn;
    const float* xrn = xgd + (size_t)ttn * G4H + k0 + hh;
    float nx0 = xrn[0], nx1 = xrn[512], nx2 = xrn[1024], nx3 = xrn[1536];

    // E. matvec partials: acc[r] = sum over my 8 cols of W[r][c]*h[c]
    float acc[16];
#pragma unroll
    for (int r = 0; r < 16; ++r) {
      float4 wa = wl0[r];
      float4 wc = wl1[r];
      float a_ = wa.x * h0.x;
      a_ = fmaf(wa.y, h0.y, a_);
      a_ = fmaf(wa.z, h0.z, a_);
      a_ = fmaf(wa.w, h0.w, a_);
      a_ = fmaf(wc.x, h1.x, a_);
      a_ = fmaf(wc.y, h1.y, a_);
      a_ = fmaf(wc.z, h1.z, a_);
      a_ = fmaf(wc.w, h1.w, a_);
      acc[r] = a_;
    }

    // log-fold butterfly: 17 shfls; ends with lane holding row (lane&15)
    float v8[8];
    {
      int b0 = lane & 1;
#pragma unroll
      for (int j = 0; j < 8; ++j) {
        float mine = b0 ? acc[2 * j + 1] : acc[2 * j];
        float oth  = b0 ? acc[2 * j] : acc[2 * j + 1];
        v8[j] = mine + __shfl_xor(oth, 1);
      }
    }
    float v4[4];
    {
      int b1 = (lane >> 1) & 1;
#pragma unroll
      for (int j = 0; j < 4; ++j) {
        float mine = b1 ? v8[2 * j + 1] : v8[2 * j];
        float oth  = b1 ? v8[2 * j] : v8[2 * j + 1];
        v4[j] = mine + __shfl_xor(oth, 2);
      }
    }
    float v2[2];
    {
      int b2 = (lane >> 2) & 1;
#pragma unroll
      for (int j = 0; j < 2; ++j) {
        float mine = b2 ? v4[2 * j + 1] : v4[2 * j];
        float oth  = b2 ? v4[2 * j] : v4[2 * j + 1];
        v2[j] = mine + __shfl_xor(oth, 4);
      }
    }
    float v1;
    {
      int b3 = (lane >> 3) & 1;
      float mine = b3 ? v2[1] : v2[0];
      float oth  = b3 ? v2[0] : v2[1];
      v1 = mine + __shfl_xor(oth, 8);
      v1 += __shfl_xor(v1, 16);
      v1 += __shfl_xor(v1, 32);
    }

    // gather the 4 gate sums for my hh (rows 4g+hh live in lanes 4g+hh)
    float si = __shfl(v1, hh + 0)  + xv0;
    float sf = __shfl(v1, hh + 4)  + xv1;
    float sg = __shfl(v1, hh + 8)  + xv2;
    float so = __shfl(v1, hh + 12) + xv3;

    float iv = sigmoidf_(si), fv = sigmoidf_(sf), gv = tanhf_(sg), ov = sigmoidf_(so);
    cst = fv * cst + iv * gv;
    float h = ov * tanhf_(cst);
    unsigned hbits = __float_as_uint(h);
    if (lane < 4) {  // lane == hh here
      if (!force_slow)  // plain write-through store -> local L2 (fast readers)
        hb_fast[(size_t)tt * HID + k0 + lane] = hbits;
      __hip_atomic_store(hb_safe + (size_t)tt * HID + k0 + lane, hbits,
                         __ATOMIC_RELAXED, __HIP_MEMORY_SCOPE_AGENT);
    }

    xv0 = nx0; xv1 = nx1; xv2 = nx2; xv3 = nx3;
  }
}

// ---------------- kernel 4: logits = h_cat @ w_out^T + b_out -----------------
__global__ __launch_bounds__(256) void out_gemm(
    const unsigned* __restrict__ hbuf, const float* __restrict__ w_out,
    const float* __restrict__ b_out, float* __restrict__ out) {
  int j0 = blockIdx.x * 128, t0 = blockIdx.y * 64;
  __shared__ float hs[64][65];
  __shared__ float ws_[128][65];
  int tid = threadIdx.x;
  int ti = tid & 15, ji = tid >> 4;
  float acc[4][8] = {};
  const float* hf = (const float*)hbuf;
  for (int kc = 0; kc < 1024; kc += 64) {
    const float* hsrc = (kc < 512) ? hf : (hf + (size_t)SEQ * HID);
    int kb = kc & 511;
#pragma unroll
    for (int i = 0; i < 4; ++i) {
      int fi = tid * 4 + i;
      int r = fi >> 4, c4 = fi & 15;
      float4 v = *(const float4*)&hsrc[(size_t)(t0 + r) * HID + kb + c4 * 4];
      hs[r][c4 * 4 + 0] = v.x; hs[r][c4 * 4 + 1] = v.y;
      hs[r][c4 * 4 + 2] = v.z; hs[r][c4 * 4 + 3] = v.w;
    }
#pragma unroll
    for (int i = 0; i < 8; ++i) {
      int fi = tid * 8 + i;
      int r = fi >> 4, c4 = fi & 15;
      float4 v = *(const float4*)&w_out[(size_t)(j0 + r) * 1024 + kc + c4 * 4];
      ws_[r][c4 * 4 + 0] = v.x; ws_[r][c4 * 4 + 1] = v.y;
      ws_[r][c4 * 4 + 2] = v.z; ws_[r][c4 * 4 + 3] = v.w;
    }
    __syncthreads();
#pragma unroll 4
    for (int kk = 0; kk < 64; ++kk) {
      float a[4], b[8];
#pragma unroll
      for (int x = 0; x < 4; ++x) a[x] = hs[ti * 4 + x][kk];
#pragma unroll
      for (int y = 0; y < 8; ++y) b[y] = ws_[ji * 8 + y][kk];
#pragma unroll
      for (int x = 0; x < 4; ++x)
#pragma unroll
        for (int y = 0; y < 8; ++y) acc[x][y] = fmaf(a[x], b[y], acc[x][y]);
    }
    __syncthreads();
  }
#pragma unroll
  for (int x = 0; x < 4; ++x)
#pragma unroll
    for (int y = 0; y < 8; ++y)
      out[(size_t)(t0 + ti * 4 + x) * TAGS + j0 + ji * 8 + y] = acc[x][y] + b_out[j0 + ji * 8 + y];
}

// ---------------- kernel 5: row-wise log_softmax in place --------------------
__global__ __launch_bounds__(256) void logsoftmax(float* __restrict__ out) {
  int t = blockIdx.x;
  float* row = out + (size_t)t * TAGS;
  int tid = threadIdx.x;
  float a = row[tid], b = row[tid + 256];
  float m = fmaxf(a, b);
  m = fmaxf(m, __shfl_xor(m, 1));
  m = fmaxf(m, __shfl_xor(m, 2));
  m = fmaxf(m, __shfl_xor(m, 4));
  m = fmaxf(m, __shfl_xor(m, 8));
  m = fmaxf(m, __shfl_xor(m, 16));
  m = fmaxf(m, __shfl_xor(m, 32));
  __shared__ float redm[4];
  __shared__ float reds[4];
  int wv = tid >> 6;
  if ((tid & 63) == 0) redm[wv] = m;
  __syncthreads();
  m = fmaxf(fmaxf(redm[0], redm[1]), fmaxf(redm[2], redm[3]));
  float s = __expf(a - m) + __expf(b - m);
  s += __shfl_xor(s, 1);
  s += __shfl_xor(s, 2);
  s += __shfl_xor(s, 4);
  s += __shfl_xor(s, 8);
  s += __shfl_xor(s, 16);
  s += __shfl_xor(s, 32);
  if ((tid & 63) == 0) reds[wv] = s;
  __syncthreads();
  s = reds[0] + reds[1] + reds[2] + reds[3];
  float ls = m + __logf(s);
  row[tid] = a - ls;
  row[tid + 256] = b - ls;
}

extern "C" void kernel_launch(void* const* d_in, const int* in_sizes, int n_in,
                              void* d_out, int out_size, void* d_ws, size_t ws_size,
                              hipStream_t stream) {
  (void)in_sizes; (void)n_in; (void)out_size;
  const float* emb    = (const float*)d_in[0];
  const float* w_ih_f = (const float*)d_in[1];
  const float* w_hh_f = (const float*)d_in[2];
  const float* b_f    = (const float*)d_in[3];
  const float* w_ih_b = (const float*)d_in[4];
  const float* w_hh_b = (const float*)d_in[5];
  const float* b_b    = (const float*)d_in[6];
  const float* w_out  = (const float*)d_in[7];
  const float* b_out  = (const float*)d_in[8];
  const int*   ids    = (const int*)d_in[9];
  const int*   seg    = (const int*)d_in[10];
  float* out = (float*)d_out;

  char* ws = (char*)d_ws;
  float*    embeds  = (float*)ws;                                  // 8 MB
  float*    xg      = (float*)(ws + (8ll << 20));                  // 128 MB
  unsigned* hb_safe = (unsigned*)(ws + (136ll << 20));             // 32 MB
  size_t need = (200ll << 20);
  int force_slow = (ws_size < need) ? 1 : 0;
  unsigned* hb_fast = force_slow ? hb_safe
                                 : (unsigned*)(ws + (168ll << 20));  // 32 MB
  unsigned* xcdtab = (unsigned*)d_out;  // 256 words; overwritten by out_gemm

  // hb_safe and hb_fast are contiguous (136..200 MB): one sentinel sweep
  int hwords = (force_slow ? 1 : 2) * 2 * SEQ * HID;
  init_sentinel<<<2048, 256, 0, stream>>>(hb_safe, hwords, xcdtab, 256);
  embed_pool<<<SEQ, 256, 0, stream>>>(emb, ids, seg, embeds);
  dim3 g2(G4H / 64, SEQ / 64, 2);
  xg_gemm<<<g2, 256, 0, stream>>>(embeds, w_ih_f, b_f, w_ih_b, b_b, xg);
  lstm_scan<<<1024, 64, 0, stream>>>(w_hh_f, w_hh_b, xg, hb_fast, hb_safe,
                                     xcdtab, force_slow);
  dim3 g4(TAGS / 128, SEQ / 64);
  out_gemm<<<g4, 256, 0, stream>>>(hb_safe, w_out, b_out, out);
  logsoftmax<<<SEQ, 256, 0, stream>>>(out);
}

// Round 13
// 12438.264 us; speedup vs baseline: 3.4913x; 1.0307x over previous
//
#include <hip/hip_runtime.h>
#include <hip/hip_bf16.h>

#define VOCAB 200000
#define EMB 256
#define HID 512
#define SEQ 8192
#define TOK 32768
#define TAGS 512
#define G4H 2048  // 4*HID

#define SENT 0x7FBFFFFFu  // NaN payload sentinel; real h is always finite

typedef unsigned u4v __attribute__((ext_vector_type(4)));

__device__ __forceinline__ float sigmoidf_(float x) { return 1.0f / (1.0f + __expf(-x)); }
__device__ __forceinline__ float tanhf_(float x) { return 1.0f - 2.0f / (1.0f + __expf(2.0f * x)); }

// ------------- kernel 0: init (both h buffers + election table) --------------
__global__ void init_sentinel(unsigned* __restrict__ hbuf, int n,
                              unsigned* __restrict__ tab, int ntab) {
  int i = blockIdx.x * blockDim.x + threadIdx.x;
  int stride = gridDim.x * blockDim.x;
  for (int k = i; k < n; k += stride) hbuf[k] = SENT;
  for (int k = i; k < ntab; k += stride) tab[k] = 0xFFFFFFFFu;
}

// ---------------- kernel 1: embedding bag (sum pool per sorted segment) ------
__global__ __launch_bounds__(256) void embed_pool(
    const float* __restrict__ emb, const int* __restrict__ ids,
    const int* __restrict__ seg, float* __restrict__ out) {
  int s = blockIdx.x;
  int d = threadIdx.x;  // 256 = EMB
  int lo = 0, hi = TOK;
  while (lo < hi) { int m = (lo + hi) >> 1; if (seg[m] < s) lo = m + 1; else hi = m; }
  int start = lo;
  hi = TOK;
  while (lo < hi) { int m = (lo + hi) >> 1; if (seg[m] < s + 1) lo = m + 1; else hi = m; }
  int end = lo;
  float acc = 0.f;
  for (int tkn = start; tkn < end; ++tkn) {
    acc += emb[(long)ids[tkn] * EMB + d];
  }
  out[s * EMB + d] = acc;
}

// ---------------- kernel 2: xg = embeds @ w_ih^T + b  (both dirs) ------------
__global__ __launch_bounds__(256) void xg_gemm(
    const float* __restrict__ embeds,
    const float* __restrict__ w_ih_f, const float* __restrict__ b_f,
    const float* __restrict__ w_ih_b, const float* __restrict__ b_b,
    float* __restrict__ xg) {
  int dir = blockIdx.z;
  const float* W = dir ? w_ih_b : w_ih_f;
  const float* B = dir ? b_b : b_f;
  float* out = xg + (size_t)dir * SEQ * G4H;
  int j0 = blockIdx.x * 64, t0 = blockIdx.y * 64;
  __shared__ float As[64][65];
  __shared__ float Bs[64][65];
  int tid = threadIdx.x;
  int ty = tid >> 4, tx = tid & 15;
  float acc[4][4] = {};
  for (int kc = 0; kc < EMB; kc += 64) {
#pragma unroll
    for (int i = 0; i < 4; ++i) {
      int fi = tid * 4 + i;
      int r = fi >> 4, c4 = fi & 15;
      float4 a = *(const float4*)&embeds[(size_t)(t0 + r) * EMB + kc + c4 * 4];
      As[r][c4 * 4 + 0] = a.x; As[r][c4 * 4 + 1] = a.y;
      As[r][c4 * 4 + 2] = a.z; As[r][c4 * 4 + 3] = a.w;
      float4 b = *(const float4*)&W[(size_t)(j0 + r) * EMB + kc + c4 * 4];
      Bs[r][c4 * 4 + 0] = b.x; Bs[r][c4 * 4 + 1] = b.y;
      Bs[r][c4 * 4 + 2] = b.z; Bs[r][c4 * 4 + 3] = b.w;
    }
    __syncthreads();
#pragma unroll 8
    for (int kk = 0; kk < 64; ++kk) {
      float a[4], b[4];
#pragma unroll
      for (int i = 0; i < 4; ++i) a[i] = As[ty * 4 + i][kk];
#pragma unroll
      for (int i = 0; i < 4; ++i) b[i] = Bs[tx * 4 + i][kk];
#pragma unroll
      for (int i = 0; i < 4; ++i)
#pragma unroll
        for (int j = 0; j < 4; ++j) acc[i][j] = fmaf(a[i], b[j], acc[i][j]);
    }
    __syncthreads();
  }
#pragma unroll
  for (int i = 0; i < 4; ++i)
#pragma unroll
    for (int j = 0; j < 4; ++j)
      out[(size_t)(t0 + ty * 4 + i) * G4H + j0 + tx * 4 + j] = acc[i][j] + B[j0 + tx * 4 + j];
}

// -------- kernel 3: LSTM scan, sc1-L2 poll, L2-only fast-path stores ---------
// Protocol/dataflow = round 12 (proven), minus the per-step hb_safe L3 store
// in the fast path. R12's residual serializer: the poll's vmcnt(0) (FIFO on
// gfx9) had to retire the previous step's agent-scope store ack (~600-900cy
// to L3) every step. Election verdict is SYMMETRIC (uniform set -> all true;
// mixed -> all false), so the protocol stays globally consistent:
//   producers: always plain-store hb_fast (L2 ack ~200cy, overlapped);
//              agent-store hb_safe only when !same (or force_slow)
//   consumers: same -> sc1 poll hb_fast, unbounded with sleep backoff (data
//              must arrive: same-XCD sc1 coherence proven R10/R12);
//              !same -> R5 L3 sentinel poll on hb_safe
//   out_gemm:  reads hb_fast (kernel-boundary release flushes L2)
__global__ __launch_bounds__(64, 1) void lstm_scan(
    const float* __restrict__ w_hh_f, const float* __restrict__ w_hh_b,
    const float* __restrict__ xg, unsigned* __restrict__ hb_fast_base,
    unsigned* __restrict__ hb_safe_base, unsigned* __restrict__ xcdtab,
    int force_slow) {
  int b = blockIdx.x;
  int sel = b & 7;
  if (sel >= 2) return;  // non-worker block
  int dir = sel;
  int Wk = b >> 3;  // 0..127
  const float* W = dir ? w_hh_b : w_hh_f;
  const float* xgd = xg + (size_t)dir * SEQ * G4H;
  unsigned* hb_fast = hb_fast_base + (size_t)dir * SEQ * HID;
  unsigned* hb_safe = hb_safe_base + (size_t)dir * SEQ * HID;

  int lane = threadIdx.x;  // 0..63
  const int hh = lane & 3;
  const int k0 = 4 * Wk;

  // publish my XCD id (HW_REG_XCC_ID = hwreg 20)
  int my_xcd = (int)(__builtin_amdgcn_s_getreg(20 | (31 << 11)) & 0xFu);
  if (lane == 0)
    __hip_atomic_store(&xcdtab[dir * 128 + Wk], (unsigned)my_xcd,
                       __ATOMIC_RELAXED, __HIP_MEMORY_SCOPE_AGENT);

  // stage W slice in LDS (overlaps other workers' publishing)
  __shared__ float4 Wl[16 * 128];  // f4 idx = r*128 + hf*64 + l
  for (int idx = lane; idx < 16 * 128; idx += 64) {
    int r = idx >> 7, c4 = idx & 127;
    int gr = 512 * (r >> 2) + k0 + (r & 3);
    Wl[idx] = *(const float4*)&W[(size_t)gr * HID + 4 * c4];
  }
  __syncthreads();

  // election read-back (symmetric verdict; see header comment)
  bool same = false;
  if (!force_slow) {
    bool ok = true;
#pragma unroll
    for (int pp = 0; pp < 2; ++pp) {
      int p = lane + 64 * pp;
      unsigned v = 0xFFFFFFFFu;
      for (int tries = 0; tries < (1 << 15); ++tries) {
        v = __hip_atomic_load(&xcdtab[dir * 128 + p], __ATOMIC_RELAXED,
                              __HIP_MEMORY_SCOPE_AGENT);
        if (v != 0xFFFFFFFFu) break;
        __builtin_amdgcn_s_sleep(4);
      }
      ok &= (v == (unsigned)my_xcd);
    }
    same = __all((int)ok);
  }

  // prologue: xg for the first step (in registers at loop entry)
  int tt0 = dir ? (SEQ - 1) : 0;
  const float* xr0 = xgd + (size_t)tt0 * G4H + k0 + hh;
  float xv0 = xr0[0], xv1 = xr0[512], xv2 = xr0[1024], xv3 = xr0[1536];

  float cst = 0.f;  // cell state for h[k0+hh] (redundant across 16-lane groups)

  for (int t = 0; t < SEQ; ++t) {
    int tt = dir ? (SEQ - 1 - t) : t;
    int pt = dir ? (tt + 1) : (tt - 1);
    unsigned* srcF = hb_fast + (size_t)pt * HID + 4 * lane;

    // A. issue first fast-poll sample before anything else
    u4v pa, pc;
    bool fastpoll = (t > 0) && same;
    if (fastpoll) {
      asm volatile(
          "global_load_dwordx4 %0, %2, off sc1\n\t"
          "global_load_dwordx4 %1, %2, off offset:1024 sc1"
          : "=&v"(pa), "=&v"(pc)
          : "v"(srcF)
          : "memory");
    }

    // B. weight slice reads (LDS; independent of h; overlap poll RTT)
    float4 wl0[16], wl1[16];
#pragma unroll
    for (int r = 0; r < 16; ++r) {
      wl0[r] = Wl[r * 128 + lane];
      wl1[r] = Wl[r * 128 + 64 + lane];
    }

    // C. resolve h_prev
    float4 h0, h1;
    if (t == 0) {
      h0 = make_float4(0.f, 0.f, 0.f, 0.f);
      h1 = make_float4(0.f, 0.f, 0.f, 0.f);
    } else {
      unsigned w0, w1, w2, w3, w4, w5, w6, w7;
      if (fastpoll) {
        // rule-#18-safe deferred wait: tie poll regs + sched fence
        asm volatile("s_waitcnt vmcnt(0)" : "+v"(pa), "+v"(pc) :: "memory");
        __builtin_amdgcn_sched_barrier(0);
        w0 = pa.x; w1 = pa.y; w2 = pa.z; w3 = pa.w;
        w4 = pc.x; w5 = pc.y; w6 = pc.z; w7 = pc.w;
        bool ok = (w0 != SENT) & (w1 != SENT) & (w2 != SENT) & (w3 != SENT) &
                  (w4 != SENT) & (w5 != SENT) & (w6 != SENT) & (w7 != SENT);
        bool got = __all((int)ok);
        // unbounded resample with backoff: data MUST arrive (same-XCD sc1
        // coherence proven); backoff keeps TCC pressure low on long waits
        for (int tries = 0; !got; ++tries) {
          u4v a, c;
          asm volatile(
              "global_load_dwordx4 %0, %2, off sc1\n\t"
              "global_load_dwordx4 %1, %2, off offset:1024 sc1\n\t"
              "s_waitcnt vmcnt(0)"
              : "=&v"(a), "=&v"(c)
              : "v"(srcF)
              : "memory");
          __builtin_amdgcn_sched_barrier(0);
          w0 = a.x; w1 = a.y; w2 = a.z; w3 = a.w;
          w4 = c.x; w5 = c.y; w6 = c.z; w7 = c.w;
          ok = (w0 != SENT) & (w1 != SENT) & (w2 != SENT) & (w3 != SENT) &
               (w4 != SENT) & (w5 != SENT) & (w6 != SENT) & (w7 != SENT);
          got = __all((int)ok);
          if (!got && tries > 64) __builtin_amdgcn_s_sleep(2);
        }
      } else {
        // proven System-scope (L3) sentinel poll on hb_safe
        unsigned* src = hb_safe + (size_t)pt * HID + 4 * lane;
        for (;;) {
          u4v a, c;
          asm volatile(
              "global_load_dwordx4 %0, %2, off sc0 sc1\n\t"
              "global_load_dwordx4 %1, %2, off offset:1024 sc0 sc1\n\t"
              "s_waitcnt vmcnt(0)"
              : "=&v"(a), "=&v"(c)
              : "v"(src)
              : "memory");
          __builtin_amdgcn_sched_barrier(0);
          w0 = a.x; w1 = a.y; w2 = a.z; w3 = a.w;
          w4 = c.x; w5 = c.y; w6 = c.z; w7 = c.w;
          bool ok = (w0 != SENT) & (w1 != SENT) & (w2 != SENT) & (w3 != SENT) &
                    (w4 != SENT) & (w5 != SENT) & (w6 != SENT) & (w7 != SENT);
          if (__all((int)ok)) break;
          __builtin_amdgcn_s_sleep(1);
        }
      }
      h0.x = __uint_as_float(w0); h0.y = __uint_as_float(w1);
      h0.z = __uint_as_float(w2); h0.w = __uint_as_float(w3);
      h1.x = __uint_as_float(w4); h1.y = __uint_as_float(w5);
      h1.z = __uint_as_float(w6); h1.w = __uint_as_float(w7);
    }

    // D. prefetch next step's xg (outside every poll's vmcnt window)
    int tn = (t + 1 < SEQ) ? (t + 1) : t;
    int ttn = dir ? (SEQ - 1 - tn) : tn;
    const float* xrn = xgd + (size_t)ttn * G4H + k0 + hh;
    float nx0 = xrn[0], nx1 = xrn[512], nx2 = xrn[1024], nx3 = xrn[1536];

    // E. matvec partials: acc[r] = sum over my 8 cols of W[r][c]*h[c]
    float acc[16];
#pragma unroll
    for (int r = 0; r < 16; ++r) {
      float4 wa = wl0[r];
      float4 wc = wl1[r];
      float a_ = wa.x * h0.x;
      a_ = fmaf(wa.y, h0.y, a_);
      a_ = fmaf(wa.z, h0.z, a_);
      a_ = fmaf(wa.w, h0.w, a_);
      a_ = fmaf(wc.x, h1.x, a_);
      a_ = fmaf(wc.y, h1.y, a_);
      a_ = fmaf(wc.z, h1.z, a_);
      a_ = fmaf(wc.w, h1.w, a_);
      acc[r] = a_;
    }

    // log-fold butterfly: 17 shfls; ends with lane holding row (lane&15)
    float v8[8];
    {
      int b0 = lane & 1;
#pragma unroll
      for (int j = 0; j < 8; ++j) {
        float mine = b0 ? acc[2 * j + 1] : acc[2 * j];
        float oth  = b0 ? acc[2 * j] : acc[2 * j + 1];
        v8[j] = mine + __shfl_xor(oth, 1);
      }
    }
    float v4[4];
    {
      int b1 = (lane >> 1) & 1;
#pragma unroll
      for (int j = 0; j < 4; ++j) {
        float mine = b1 ? v8[2 * j + 1] : v8[2 * j];
        float oth  = b1 ? v8[2 * j] : v8[2 * j + 1];
        v4[j] = mine + __shfl_xor(oth, 2);
      }
    }
    float v2[2];
    {
      int b2 = (lane >> 2) & 1;
#pragma unroll
      for (int j = 0; j < 2; ++j) {
        float mine = b2 ? v4[2 * j + 1] : v4[2 * j];
        float oth  = b2 ? v4[2 * j] : v4[2 * j + 1];
        v2[j] = mine + __shfl_xor(oth, 4);
      }
    }
    float v1;
    {
      int b3 = (lane >> 3) & 1;
      float mine = b3 ? v2[1] : v2[0];
      float oth  = b3 ? v2[0] : v2[1];
      v1 = mine + __shfl_xor(oth, 8);
      v1 += __shfl_xor(v1, 16);
      v1 += __shfl_xor(v1, 32);
    }

    // gather the 4 gate sums for my hh (rows 4g+hh live in lanes 4g+hh)
    float si = __shfl(v1, hh + 0)  + xv0;
    float sf = __shfl(v1, hh + 4)  + xv1;
    float sg = __shfl(v1, hh + 8)  + xv2;
    float so = __shfl(v1, hh + 12) + xv3;

    float iv = sigmoidf_(si), fv = sigmoidf_(sf), gv = tanhf_(sg), ov = sigmoidf_(so);
    cst = fv * cst + iv * gv;
    float h = ov * tanhf_(cst);
    unsigned hbits = __float_as_uint(h);
    if (lane < 4) {  // lane == hh here
      // always: plain store -> local L2 (fast readers + out_gemm)
      hb_fast[(size_t)tt * HID + k0 + lane] = hbits;
      // only when the slow protocol is active: agent store -> L3
      if (!same)
        __hip_atomic_store(hb_safe + (size_t)tt * HID + k0 + lane, hbits,
                           __ATOMIC_RELAXED, __HIP_MEMORY_SCOPE_AGENT);
    }

    xv0 = nx0; xv1 = nx1; xv2 = nx2; xv3 = nx3;
  }
}

// ---------------- kernel 4: logits = h_cat @ w_out^T + b_out -----------------
__global__ __launch_bounds__(256) void out_gemm(
    const unsigned* __restrict__ hbuf, const float* __restrict__ w_out,
    const float* __restrict__ b_out, float* __restrict__ out) {
  int j0 = blockIdx.x * 128, t0 = blockIdx.y * 64;
  __shared__ float hs[64][65];
  __shared__ float ws_[128][65];
  int tid = threadIdx.x;
  int ti = tid & 15, ji = tid >> 4;
  float acc[4][8] = {};
  const float* hf = (const float*)hbuf;
  for (int kc = 0; kc < 1024; kc += 64) {
    const float* hsrc = (kc < 512) ? hf : (hf + (size_t)SEQ * HID);
    int kb = kc & 511;
#pragma unroll
    for (int i = 0; i < 4; ++i) {
      int fi = tid * 4 + i;
      int r = fi >> 4, c4 = fi & 15;
      float4 v = *(const float4*)&hsrc[(size_t)(t0 + r) * HID + kb + c4 * 4];
      hs[r][c4 * 4 + 0] = v.x; hs[r][c4 * 4 + 1] = v.y;
      hs[r][c4 * 4 + 2] = v.z; hs[r][c4 * 4 + 3] = v.w;
    }
#pragma unroll
    for (int i = 0; i < 8; ++i) {
      int fi = tid * 8 + i;
      int r = fi >> 4, c4 = fi & 15;
      float4 v = *(const float4*)&w_out[(size_t)(j0 + r) * 1024 + kc + c4 * 4];
      ws_[r][c4 * 4 + 0] = v.x; ws_[r][c4 * 4 + 1] = v.y;
      ws_[r][c4 * 4 + 2] = v.z; ws_[r][c4 * 4 + 3] = v.w;
    }
    __syncthreads();
#pragma unroll 4
    for (int kk = 0; kk < 64; ++kk) {
      float a[4], b[8];
#pragma unroll
      for (int x = 0; x < 4; ++x) a[x] = hs[ti * 4 + x][kk];
#pragma unroll
      for (int y = 0; y < 8; ++y) b[y] = ws_[ji * 8 + y][kk];
#pragma unroll
      for (int x = 0; x < 4; ++x)
#pragma unroll
        for (int y = 0; y < 8; ++y) acc[x][y] = fmaf(a[x], b[y], acc[x][y]);
    }
    __syncthreads();
  }
#pragma unroll
  for (int x = 0; x < 4; ++x)
#pragma unroll
    for (int y = 0; y < 8; ++y)
      out[(size_t)(t0 + ti * 4 + x) * TAGS + j0 + ji * 8 + y] = acc[x][y] + b_out[j0 + ji * 8 + y];
}

// ---------------- kernel 5: row-wise log_softmax in place --------------------
__global__ __launch_bounds__(256) void logsoftmax(float* __restrict__ out) {
  int t = blockIdx.x;
  float* row = out + (size_t)t * TAGS;
  int tid = threadIdx.x;
  float a = row[tid], b = row[tid + 256];
  float m = fmaxf(a, b);
  m = fmaxf(m, __shfl_xor(m, 1));
  m = fmaxf(m, __shfl_xor(m, 2));
  m = fmaxf(m, __shfl_xor(m, 4));
  m = fmaxf(m, __shfl_xor(m, 8));
  m = fmaxf(m, __shfl_xor(m, 16));
  m = fmaxf(m, __shfl_xor(m, 32));
  __shared__ float redm[4];
  __shared__ float reds[4];
  int wv = tid >> 6;
  if ((tid & 63) == 0) redm[wv] = m;
  __syncthreads();
  m = fmaxf(fmaxf(redm[0], redm[1]), fmaxf(redm[2], redm[3]));
  float s = __expf(a - m) + __expf(b - m);
  s += __shfl_xor(s, 1);
  s += __shfl_xor(s, 2);
  s += __shfl_xor(s, 4);
  s += __shfl_xor(s, 8);
  s += __shfl_xor(s, 16);
  s += __shfl_xor(s, 32);
  if ((tid & 63) == 0) reds[wv] = s;
  __syncthreads();
  s = reds[0] + reds[1] + reds[2] + reds[3];
  float ls = m + __logf(s);
  row[tid] = a - ls;
  row[tid + 256] = b - ls;
}

extern "C" void kernel_launch(void* const* d_in, const int* in_sizes, int n_in,
                              void* d_out, int out_size, void* d_ws, size_t ws_size,
                              hipStream_t stream) {
  (void)in_sizes; (void)n_in; (void)out_size;
  const float* emb    = (const float*)d_in[0];
  const float* w_ih_f = (const float*)d_in[1];
  const float* w_hh_f = (const float*)d_in[2];
  const float* b_f    = (const float*)d_in[3];
  const float* w_ih_b = (const float*)d_in[4];
  const float* w_hh_b = (const float*)d_in[5];
  const float* b_b    = (const float*)d_in[6];
  const float* w_out  = (const float*)d_in[7];
  const float* b_out  = (const float*)d_in[8];
  const int*   ids    = (const int*)d_in[9];
  const int*   seg    = (const int*)d_in[10];
  float* out = (float*)d_out;

  char* ws = (char*)d_ws;
  float*    embeds  = (float*)ws;                                  // 8 MB
  float*    xg      = (float*)(ws + (8ll << 20));                  // 128 MB
  unsigned* hb_safe = (unsigned*)(ws + (136ll << 20));             // 32 MB
  size_t need = (200ll << 20);
  int force_slow = (ws_size < need) ? 1 : 0;
  unsigned* hb_fast = force_slow ? hb_safe
                                 : (unsigned*)(ws + (168ll << 20));  // 32 MB
  unsigned* xcdtab = (unsigned*)d_out;  // 256 words; overwritten by out_gemm

  // hb_safe and hb_fast are contiguous (136..200 MB): one sentinel sweep
  int hwords = (force_slow ? 1 : 2) * 2 * SEQ * HID;
  init_sentinel<<<2048, 256, 0, stream>>>(hb_safe, hwords, xcdtab, 256);
  embed_pool<<<SEQ, 256, 0, stream>>>(emb, ids, seg, embeds);
  dim3 g2(G4H / 64, SEQ / 64, 2);
  xg_gemm<<<g2, 256, 0, stream>>>(embeds, w_ih_f, b_f, w_ih_b, b_b, xg);
  lstm_scan<<<1024, 64, 0, stream>>>(w_hh_f, w_hh_b, xg, hb_fast, hb_safe,
                                     xcdtab, force_slow);
  dim3 g4(TAGS / 128, SEQ / 64);
  out_gemm<<<g4, 256, 0, stream>>>(hb_fast, w_out, b_out, out);
  logsoftmax<<<SEQ, 256, 0, stream>>>(out);
}

// Round 14
// 11677.780 us; speedup vs baseline: 3.7186x; 1.0651x over previous
//
#include <hip/hip_runtime.h>
#include <hip/hip_bf16.h>

#define VOCAB 200000
#define EMB 256
#define HID 512
#define SEQ 8192
#define TOK 32768
#define TAGS 512
#define G4H 2048  // 4*HID

#define SENT 0x7FBFFFFFu  // NaN payload sentinel; real h is always finite

typedef unsigned u4v __attribute__((ext_vector_type(4)));

__device__ __forceinline__ float sigmoidf_(float x) { return 1.0f / (1.0f + __expf(-x)); }
__device__ __forceinline__ float tanhf_(float x) { return 1.0f - 2.0f / (1.0f + __expf(2.0f * x)); }

// ------------- kernel 0: init (both h buffers + election table) --------------
__global__ void init_sentinel(unsigned* __restrict__ hbuf, int n,
                              unsigned* __restrict__ tab, int ntab) {
  int i = blockIdx.x * blockDim.x + threadIdx.x;
  int stride = gridDim.x * blockDim.x;
  for (int k = i; k < n; k += stride) hbuf[k] = SENT;
  for (int k = i; k < ntab; k += stride) tab[k] = 0xFFFFFFFFu;
}

// ---------------- kernel 1: embedding bag (sum pool per sorted segment) ------
__global__ __launch_bounds__(256) void embed_pool(
    const float* __restrict__ emb, const int* __restrict__ ids,
    const int* __restrict__ seg, float* __restrict__ out) {
  int s = blockIdx.x;
  int d = threadIdx.x;  // 256 = EMB
  int lo = 0, hi = TOK;
  while (lo < hi) { int m = (lo + hi) >> 1; if (seg[m] < s) lo = m + 1; else hi = m; }
  int start = lo;
  hi = TOK;
  while (lo < hi) { int m = (lo + hi) >> 1; if (seg[m] < s + 1) lo = m + 1; else hi = m; }
  int end = lo;
  float acc = 0.f;
  for (int tkn = start; tkn < end; ++tkn) {
    acc += emb[(long)ids[tkn] * EMB + d];
  }
  out[s * EMB + d] = acc;
}

// ---------------- kernel 2: xg = embeds @ w_ih^T + b  (both dirs) ------------
__global__ __launch_bounds__(256) void xg_gemm(
    const float* __restrict__ embeds,
    const float* __restrict__ w_ih_f, const float* __restrict__ b_f,
    const float* __restrict__ w_ih_b, const float* __restrict__ b_b,
    float* __restrict__ xg) {
  int dir = blockIdx.z;
  const float* W = dir ? w_ih_b : w_ih_f;
  const float* B = dir ? b_b : b_f;
  float* out = xg + (size_t)dir * SEQ * G4H;
  int j0 = blockIdx.x * 64, t0 = blockIdx.y * 64;
  __shared__ float As[64][65];
  __shared__ float Bs[64][65];
  int tid = threadIdx.x;
  int ty = tid >> 4, tx = tid & 15;
  float acc[4][4] = {};
  for (int kc = 0; kc < EMB; kc += 64) {
#pragma unroll
    for (int i = 0; i < 4; ++i) {
      int fi = tid * 4 + i;
      int r = fi >> 4, c4 = fi & 15;
      float4 a = *(const float4*)&embeds[(size_t)(t0 + r) * EMB + kc + c4 * 4];
      As[r][c4 * 4 + 0] = a.x; As[r][c4 * 4 + 1] = a.y;
      As[r][c4 * 4 + 2] = a.z; As[r][c4 * 4 + 3] = a.w;
      float4 b = *(const float4*)&W[(size_t)(j0 + r) * EMB + kc + c4 * 4];
      Bs[r][c4 * 4 + 0] = b.x; Bs[r][c4 * 4 + 1] = b.y;
      Bs[r][c4 * 4 + 2] = b.z; Bs[r][c4 * 4 + 3] = b.w;
    }
    __syncthreads();
#pragma unroll 8
    for (int kk = 0; kk < 64; ++kk) {
      float a[4], b[4];
#pragma unroll
      for (int i = 0; i < 4; ++i) a[i] = As[ty * 4 + i][kk];
#pragma unroll
      for (int i = 0; i < 4; ++i) b[i] = Bs[tx * 4 + i][kk];
#pragma unroll
      for (int i = 0; i < 4; ++i)
#pragma unroll
        for (int j = 0; j < 4; ++j) acc[i][j] = fmaf(a[i], b[j], acc[i][j]);
    }
    __syncthreads();
  }
#pragma unroll
  for (int i = 0; i < 4; ++i)
#pragma unroll
    for (int j = 0; j < 4; ++j)
      out[(size_t)(t0 + ty * 4 + i) * G4H + j0 + tx * 4 + j] = acc[i][j] + B[j0 + tx * 4 + j];
}

// -- kernel 3: LSTM scan, sc1-L2 poll, 2 h/WG geometry (2 waves per SIMD) -----
// Protocol = round 13 (proven): sc1 fast poll on hb_fast, plain L2 stores,
// symmetric election, sticky L3 fallback on hb_safe. Geometry change: 256
// WGs/dir each owning 2 h (8 gate rows x 512 cols, 16KB LDS slice) -> 8
// WGs/CU on each of 2 XCDs -> 2 waves/SIMD. One wave's poll stall is hidden
// by the co-resident wave's FMA/reduce; per-wave compute halves (64 FMAs,
// 14-shfl reduce). R13 evidence: 1 wave/SIMD left ~2/3 of cycles stalled.
__global__ __launch_bounds__(64) void lstm_scan(
    const float* __restrict__ w_hh_f, const float* __restrict__ w_hh_b,
    const float* __restrict__ xg, unsigned* __restrict__ hb_fast_base,
    unsigned* __restrict__ hb_safe_base, unsigned* __restrict__ xcdtab,
    int force_slow) {
  int b = blockIdx.x;
  int sel = b & 7;
  if (sel >= 2) return;  // non-worker block
  int dir = sel;
  int Wk = b >> 3;  // 0..255
  const float* W = dir ? w_hh_b : w_hh_f;
  const float* xgd = xg + (size_t)dir * SEQ * G4H;
  unsigned* hb_fast = hb_fast_base + (size_t)dir * SEQ * HID;
  unsigned* hb_safe = hb_safe_base + (size_t)dir * SEQ * HID;

  int lane = threadIdx.x;  // 0..63
  const int hh = lane & 1;
  const int k0 = 2 * Wk;

  // publish my XCD id (HW_REG_XCC_ID = hwreg 20)
  int my_xcd = (int)(__builtin_amdgcn_s_getreg(20 | (31 << 11)) & 0xFu);
  if (lane == 0)
    __hip_atomic_store(&xcdtab[dir * 256 + Wk], (unsigned)my_xcd,
                       __ATOMIC_RELAXED, __HIP_MEMORY_SCOPE_AGENT);

  // stage W slice in LDS: 8 rows x 512 cols = 16KB
  // LDS row r <-> global gate row 512*(r>>1) + k0 + (r&1)
  __shared__ float4 Wl[8 * 128];  // f4 idx = r*128 + hf*64 + l
  for (int idx = lane; idx < 8 * 128; idx += 64) {
    int r = idx >> 7, c4 = idx & 127;
    int gr = 512 * (r >> 1) + k0 + (r & 1);
    Wl[idx] = *(const float4*)&W[(size_t)gr * HID + 4 * c4];
  }
  __syncthreads();

  // election read-back (symmetric verdict): 256 producers per direction
  bool same = false;
  if (!force_slow) {
    bool ok = true;
#pragma unroll
    for (int pp = 0; pp < 4; ++pp) {
      int p = lane + 64 * pp;
      unsigned v = 0xFFFFFFFFu;
      for (int tries = 0; tries < (1 << 15); ++tries) {
        v = __hip_atomic_load(&xcdtab[dir * 256 + p], __ATOMIC_RELAXED,
                              __HIP_MEMORY_SCOPE_AGENT);
        if (v != 0xFFFFFFFFu) break;
        __builtin_amdgcn_s_sleep(4);
      }
      ok &= (v == (unsigned)my_xcd);
    }
    same = __all((int)ok);
  }

  // prologue: xg for the first step (in registers at loop entry)
  int tt0 = dir ? (SEQ - 1) : 0;
  const float* xr0 = xgd + (size_t)tt0 * G4H + k0 + hh;
  float xv0 = xr0[0], xv1 = xr0[512], xv2 = xr0[1024], xv3 = xr0[1536];

  float cst = 0.f;  // cell state for h[k0+hh] (redundant across parity lanes)

  for (int t = 0; t < SEQ; ++t) {
    int tt = dir ? (SEQ - 1 - t) : t;
    int pt = dir ? (tt + 1) : (tt - 1);
    unsigned* srcF = hb_fast + (size_t)pt * HID + 4 * lane;

    // A. issue first fast-poll sample before anything else
    u4v pa, pc;
    bool fastpoll = (t > 0) && same;
    if (fastpoll) {
      asm volatile(
          "global_load_dwordx4 %0, %2, off sc1\n\t"
          "global_load_dwordx4 %1, %2, off offset:1024 sc1"
          : "=&v"(pa), "=&v"(pc)
          : "v"(srcF)
          : "memory");
    }

    // B. weight slice reads (LDS; independent of h; overlap poll RTT)
    float4 wl0[8], wl1[8];
#pragma unroll
    for (int r = 0; r < 8; ++r) {
      wl0[r] = Wl[r * 128 + lane];
      wl1[r] = Wl[r * 128 + 64 + lane];
    }

    // C. resolve h_prev
    float4 h0, h1;
    if (t == 0) {
      h0 = make_float4(0.f, 0.f, 0.f, 0.f);
      h1 = make_float4(0.f, 0.f, 0.f, 0.f);
    } else {
      unsigned w0, w1, w2, w3, w4, w5, w6, w7;
      if (fastpoll) {
        // rule-#18-safe deferred wait: tie poll regs + sched fence
        asm volatile("s_waitcnt vmcnt(0)" : "+v"(pa), "+v"(pc) :: "memory");
        __builtin_amdgcn_sched_barrier(0);
        w0 = pa.x; w1 = pa.y; w2 = pa.z; w3 = pa.w;
        w4 = pc.x; w5 = pc.y; w6 = pc.z; w7 = pc.w;
        bool ok = (w0 != SENT) & (w1 != SENT) & (w2 != SENT) & (w3 != SENT) &
                  (w4 != SENT) & (w5 != SENT) & (w6 != SENT) & (w7 != SENT);
        bool got = __all((int)ok);
        for (int tries = 0; !got; ++tries) {
          u4v a, c;
          asm volatile(
              "global_load_dwordx4 %0, %2, off sc1\n\t"
              "global_load_dwordx4 %1, %2, off offset:1024 sc1\n\t"
              "s_waitcnt vmcnt(0)"
              : "=&v"(a), "=&v"(c)
              : "v"(srcF)
              : "memory");
          __builtin_amdgcn_sched_barrier(0);
          w0 = a.x; w1 = a.y; w2 = a.z; w3 = a.w;
          w4 = c.x; w5 = c.y; w6 = c.z; w7 = c.w;
          ok = (w0 != SENT) & (w1 != SENT) & (w2 != SENT) & (w3 != SENT) &
               (w4 != SENT) & (w5 != SENT) & (w6 != SENT) & (w7 != SENT);
          got = __all((int)ok);
          if (!got && tries > 64) __builtin_amdgcn_s_sleep(2);
        }
      } else {
        // proven System-scope (L3) sentinel poll on hb_safe
        unsigned* src = hb_safe + (size_t)pt * HID + 4 * lane;
        for (;;) {
          u4v a, c;
          asm volatile(
              "global_load_dwordx4 %0, %2, off sc0 sc1\n\t"
              "global_load_dwordx4 %1, %2, off offset:1024 sc0 sc1\n\t"
              "s_waitcnt vmcnt(0)"
              : "=&v"(a), "=&v"(c)
              : "v"(src)
              : "memory");
          __builtin_amdgcn_sched_barrier(0);
          w0 = a.x; w1 = a.y; w2 = a.z; w3 = a.w;
          w4 = c.x; w5 = c.y; w6 = c.z; w7 = c.w;
          bool ok = (w0 != SENT) & (w1 != SENT) & (w2 != SENT) & (w3 != SENT) &
                    (w4 != SENT) & (w5 != SENT) & (w6 != SENT) & (w7 != SENT);
          if (__all((int)ok)) break;
          __builtin_amdgcn_s_sleep(1);
        }
      }
      h0.x = __uint_as_float(w0); h0.y = __uint_as_float(w1);
      h0.z = __uint_as_float(w2); h0.w = __uint_as_float(w3);
      h1.x = __uint_as_float(w4); h1.y = __uint_as_float(w5);
      h1.z = __uint_as_float(w6); h1.w = __uint_as_float(w7);
    }

    // D. prefetch next step's xg (outside every poll's vmcnt window)
    int tn = (t + 1 < SEQ) ? (t + 1) : t;
    int ttn = dir ? (SEQ - 1 - tn) : tn;
    const float* xrn = xgd + (size_t)ttn * G4H + k0 + hh;
    float nx0 = xrn[0], nx1 = xrn[512], nx2 = xrn[1024], nx3 = xrn[1536];

    // E. matvec partials: acc[r] = sum over my 8 cols of W[r][c]*h[c]
    float acc[8];
#pragma unroll
    for (int r = 0; r < 8; ++r) {
      float4 wa = wl0[r];
      float4 wc = wl1[r];
      float a_ = wa.x * h0.x;
      a_ = fmaf(wa.y, h0.y, a_);
      a_ = fmaf(wa.z, h0.z, a_);
      a_ = fmaf(wa.w, h0.w, a_);
      a_ = fmaf(wc.x, h1.x, a_);
      a_ = fmaf(wc.y, h1.y, a_);
      a_ = fmaf(wc.z, h1.z, a_);
      a_ = fmaf(wc.w, h1.w, a_);
      acc[r] = a_;
    }

    // log-fold: 3 fold stages (xor1,2,4) + 3 butterflies (xor8,16,32);
    // ends with every lane holding the FULL sum of row (lane&7)
    float v4[4];
    {
      int b0 = lane & 1;
#pragma unroll
      for (int j = 0; j < 4; ++j) {
        float mine = b0 ? acc[2 * j + 1] : acc[2 * j];
        float oth  = b0 ? acc[2 * j] : acc[2 * j + 1];
        v4[j] = mine + __shfl_xor(oth, 1);
      }
    }
    float v2[2];
    {
      int b1 = (lane >> 1) & 1;
#pragma unroll
      for (int j = 0; j < 2; ++j) {
        float mine = b1 ? v4[2 * j + 1] : v4[2 * j];
        float oth  = b1 ? v4[2 * j] : v4[2 * j + 1];
        v2[j] = mine + __shfl_xor(oth, 2);
      }
    }
    float v1;
    {
      int b2 = (lane >> 2) & 1;
      float mine = b2 ? v2[1] : v2[0];
      float oth  = b2 ? v2[0] : v2[1];
      v1 = mine + __shfl_xor(oth, 4);
      v1 += __shfl_xor(v1, 8);
      v1 += __shfl_xor(v1, 16);
      v1 += __shfl_xor(v1, 32);
    }

    // gather the 4 gate sums for my hh (row 2g+hh lives in lane 2g+hh)
    float si = __shfl(v1, hh + 0) + xv0;
    float sf = __shfl(v1, hh + 2) + xv1;
    float sg = __shfl(v1, hh + 4) + xv2;
    float so = __shfl(v1, hh + 6) + xv3;

    float iv = sigmoidf_(si), fv = sigmoidf_(sf), gv = tanhf_(sg), ov = sigmoidf_(so);
    cst = fv * cst + iv * gv;
    float h = ov * tanhf_(cst);
    unsigned hbits = __float_as_uint(h);
    if (lane < 2) {  // lane == hh here
      // always: plain store -> local L2 (fast readers + out_gemm)
      hb_fast[(size_t)tt * HID + k0 + lane] = hbits;
      // only when the slow protocol is active: agent store -> L3
      if (!same)
        __hip_atomic_store(hb_safe + (size_t)tt * HID + k0 + lane, hbits,
                           __ATOMIC_RELAXED, __HIP_MEMORY_SCOPE_AGENT);
    }

    xv0 = nx0; xv1 = nx1; xv2 = nx2; xv3 = nx3;
  }
}

// ---------------- kernel 4: logits = h_cat @ w_out^T + b_out -----------------
__global__ __launch_bounds__(256) void out_gemm(
    const unsigned* __restrict__ hbuf, const float* __restrict__ w_out,
    const float* __restrict__ b_out, float* __restrict__ out) {
  int j0 = blockIdx.x * 128, t0 = blockIdx.y * 64;
  __shared__ float hs[64][65];
  __shared__ float ws_[128][65];
  int tid = threadIdx.x;
  int ti = tid & 15, ji = tid >> 4;
  float acc[4][8] = {};
  const float* hf = (const float*)hbuf;
  for (int kc = 0; kc < 1024; kc += 64) {
    const float* hsrc = (kc < 512) ? hf : (hf + (size_t)SEQ * HID);
    int kb = kc & 511;
#pragma unroll
    for (int i = 0; i < 4; ++i) {
      int fi = tid * 4 + i;
      int r = fi >> 4, c4 = fi & 15;
      float4 v = *(const float4*)&hsrc[(size_t)(t0 + r) * HID + kb + c4 * 4];
      hs[r][c4 * 4 + 0] = v.x; hs[r][c4 * 4 + 1] = v.y;
      hs[r][c4 * 4 + 2] = v.z; hs[r][c4 * 4 + 3] = v.w;
    }
#pragma unroll
    for (int i = 0; i < 8; ++i) {
      int fi = tid * 8 + i;
      int r = fi >> 4, c4 = fi & 15;
      float4 v = *(const float4*)&w_out[(size_t)(j0 + r) * 1024 + kc + c4 * 4];
      ws_[r][c4 * 4 + 0] = v.x; ws_[r][c4 * 4 + 1] = v.y;
      ws_[r][c4 * 4 + 2] = v.z; ws_[r][c4 * 4 + 3] = v.w;
    }
    __syncthreads();
#pragma unroll 4
    for (int kk = 0; kk < 64; ++kk) {
      float a[4], b[8];
#pragma unroll
      for (int x = 0; x < 4; ++x) a[x] = hs[ti * 4 + x][kk];
#pragma unroll
      for (int y = 0; y < 8; ++y) b[y] = ws_[ji * 8 + y][kk];
#pragma unroll
      for (int x = 0; x < 4; ++x)
#pragma unroll
        for (int y = 0; y < 8; ++y) acc[x][y] = fmaf(a[x], b[y], acc[x][y]);
    }
    __syncthreads();
  }
#pragma unroll
  for (int x = 0; x < 4; ++x)
#pragma unroll
    for (int y = 0; y < 8; ++y)
      out[(size_t)(t0 + ti * 4 + x) * TAGS + j0 + ji * 8 + y] = acc[x][y] + b_out[j0 + ji * 8 + y];
}

// ---------------- kernel 5: row-wise log_softmax in place --------------------
__global__ __launch_bounds__(256) void logsoftmax(float* __restrict__ out) {
  int t = blockIdx.x;
  float* row = out + (size_t)t * TAGS;
  int tid = threadIdx.x;
  float a = row[tid], b = row[tid + 256];
  float m = fmaxf(a, b);
  m = fmaxf(m, __shfl_xor(m, 1));
  m = fmaxf(m, __shfl_xor(m, 2));
  m = fmaxf(m, __shfl_xor(m, 4));
  m = fmaxf(m, __shfl_xor(m, 8));
  m = fmaxf(m, __shfl_xor(m, 16));
  m = fmaxf(m, __shfl_xor(m, 32));
  __shared__ float redm[4];
  __shared__ float reds[4];
  int wv = tid >> 6;
  if ((tid & 63) == 0) redm[wv] = m;
  __syncthreads();
  m = fmaxf(fmaxf(redm[0], redm[1]), fmaxf(redm[2], redm[3]));
  float s = __expf(a - m) + __expf(b - m);
  s += __shfl_xor(s, 1);
  s += __shfl_xor(s, 2);
  s += __shfl_xor(s, 4);
  s += __shfl_xor(s, 8);
  s += __shfl_xor(s, 16);
  s += __shfl_xor(s, 32);
  if ((tid & 63) == 0) reds[wv] = s;
  __syncthreads();
  s = reds[0] + reds[1] + reds[2] + reds[3];
  float ls = m + __logf(s);
  row[tid] = a - ls;
  row[tid + 256] = b - ls;
}

extern "C" void kernel_launch(void* const* d_in, const int* in_sizes, int n_in,
                              void* d_out, int out_size, void* d_ws, size_t ws_size,
                              hipStream_t stream) {
  (void)in_sizes; (void)n_in; (void)out_size;
  const float* emb    = (const float*)d_in[0];
  const float* w_ih_f = (const float*)d_in[1];
  const float* w_hh_f = (const float*)d_in[2];
  const float* b_f    = (const float*)d_in[3];
  const float* w_ih_b = (const float*)d_in[4];
  const float* w_hh_b = (const float*)d_in[5];
  const float* b_b    = (const float*)d_in[6];
  const float* w_out  = (const float*)d_in[7];
  const float* b_out  = (const float*)d_in[8];
  const int*   ids    = (const int*)d_in[9];
  const int*   seg    = (const int*)d_in[10];
  float* out = (float*)d_out;

  char* ws = (char*)d_ws;
  float*    embeds  = (float*)ws;                                  // 8 MB
  float*    xg      = (float*)(ws + (8ll << 20));                  // 128 MB
  unsigned* hb_safe = (unsigned*)(ws + (136ll << 20));             // 32 MB
  size_t need = (200ll << 20);
  int force_slow = (ws_size < need) ? 1 : 0;
  unsigned* hb_fast = force_slow ? hb_safe
                                 : (unsigned*)(ws + (168ll << 20));  // 32 MB
  unsigned* xcdtab = (unsigned*)d_out;  // 512 words; overwritten by out_gemm

  // hb_safe and hb_fast are contiguous (136..200 MB): one sentinel sweep
  int hwords = (force_slow ? 1 : 2) * 2 * SEQ * HID;
  init_sentinel<<<2048, 256, 0, stream>>>(hb_safe, hwords, xcdtab, 512);
  embed_pool<<<SEQ, 256, 0, stream>>>(emb, ids, seg, embeds);
  dim3 g2(G4H / 64, SEQ / 64, 2);
  xg_gemm<<<g2, 256, 0, stream>>>(embeds, w_ih_f, b_f, w_ih_b, b_b, xg);
  lstm_scan<<<2048, 64, 0, stream>>>(w_hh_f, w_hh_b, xg, hb_fast, hb_safe,
                                     xcdtab, force_slow);
  dim3 g4(TAGS / 128, SEQ / 64);
  out_gemm<<<g4, 256, 0, stream>>>(hb_fast, w_out, b_out, out);
  logsoftmax<<<SEQ, 256, 0, stream>>>(out);
}